// Round 1
// 179.639 us; speedup vs baseline: 1.4129x; 1.4129x over previous
//
#include <hip/hip_runtime.h>
#include <hip/hip_bf16.h>
#include <math.h>

#define B_  16
#define L_  3600
#define LAT 64
#define DM  128
#define DI  256
#define DS  16
#define DR  8

#define TT  30    // K1 time-tile
#define NT  120   // 3600/30
#define TC  100   // scan chunk length
#define NC  36    // 3600/100
#define THR (-20.0f)   // exp(a*S) < exp(-20) ~ 2e-9 -> negligible

__device__ __forceinline__ float siluf(float v) {
    return v * __builtin_amdgcn_rcpf(1.0f + __expf(-v));
}
__device__ __forceinline__ float softplusf(float v) {
    float r = __logf(1.0f + __expf(v));
    return (v > 15.0f) ? v : r;
}
__device__ __forceinline__ float bf2f(unsigned short u) {
    unsigned int x = ((unsigned int)u) << 16;
    return __builtin_bit_cast(float, x);
}
__device__ __forceinline__ unsigned short f2bf(float f) {
    __hip_bfloat16 h = __float2bfloat16(f);
    return __builtin_bit_cast(unsigned short, h);
}

// ---------------------------------------------------------------- K0: W1 = in_proj_x @ emb_w, b1 = in_proj_x @ emb_b
__global__ __launch_bounds__(64) void k0_combine(
    const float* __restrict__ in_proj_w, const float* __restrict__ emb_w,
    const float* __restrict__ emb_b, float* __restrict__ W1, float* __restrict__ b1)
{
    int d = blockIdx.x, k = threadIdx.x;
    const float* row = in_proj_w + (size_t)d * DM;
    float acc = 0.f;
    for (int m = 0; m < DM; ++m) acc += row[m] * emb_w[m * LAT + k];
    W1[d * LAT + k] = acc;
    if (k == 0) {
        float ab = 0.f;
        for (int m = 0; m < DM; ++m) ab += row[m] * emb_b[m];
        b1[d] = ab;
    }
}

// ---------------------------------------------------------------- K1: z -> x_pre -> conv -> silu -> x (store) -> x_proj(24 rows)
// Restructured: z tile staged once into LDS (broadcast ds_reads in phase A),
// xt tile in bf16 (matches x_bf exactly) -> LDS 52.9KB -> 3 blocks/CU.
__global__ __launch_bounds__(256, 3) void k1_front(
    const float* __restrict__ z, const float* __restrict__ conv_w,
    const float* __restrict__ conv_b, const float* __restrict__ x_proj_w,
    const float* __restrict__ W1, const float* __restrict__ b1,
    float* __restrict__ dtin, float* __restrict__ Bssm,
    __hip_bfloat16* __restrict__ x_bf)
{
    __shared__ float zt[TT + 3][LAT];          // 33*64*4  = 8448 B (z tile incl 3-row history)
    __shared__ unsigned short xt[TT][DI + 8];  // 30*264*2 = 15840 B (bf16 x tile, t-major)
    __shared__ float xw[DI][28];               // 28672 B  (x_proj rows 0..23 transposed, padded)

    int b = blockIdx.y, tile = blockIdx.x;
    int t0 = tile * TT;
    int tid = threadIdx.x;

    // ---- stage z tile (rows t0-3 .. t0+TT-1), zeros for t<0
    {
        const float* zb = z + (size_t)b * L_ * LAT;
        for (int i = tid; i < (TT + 3) * 16; i += 256) {  // i indexes float4 slots
            int r = i >> 4, q = i & 15;
            int t = t0 - 3 + r;
            float4 v = make_float4(0.f, 0.f, 0.f, 0.f);
            if (t >= 0) v = ((const float4*)(zb + (size_t)t * LAT))[q];
            ((float4*)&zt[r][0])[q] = v;
        }
    }
    // ---- stage x_proj (24x256) transposed
    for (int i = tid; i < 24 * DI; i += 256) {
        int j = i / DI, k = i % DI;
        xw[k][j] = x_proj_w[j * DI + k];
    }

    // ---- per-thread weights (issued before sync so latency overlaps staging)
    int d = tid;
    float w1r[LAT];
    {
        const float4* wp = (const float4*)(W1 + d * LAT);
        #pragma unroll
        for (int q = 0; q < 16; ++q) {
            float4 v = wp[q];
            w1r[4*q] = v.x; w1r[4*q+1] = v.y; w1r[4*q+2] = v.z; w1r[4*q+3] = v.w;
        }
    }
    float4 cw = *(const float4*)(conv_w + d * 4);
    float cb = conv_b[d];
    float bias = b1[d];
    __syncthreads();

    // ---- phase A: thread owns channel d; rolling conv window over t, z from LDS (broadcast)
    float xp0 = 0.f, xp1 = 0.f, xp2 = 0.f, xp3 = 0.f;
    for (int j = 0; j < TT + 3; ++j) {
        int t = t0 - 3 + j;
        const float4* zr = (const float4*)&zt[j][0];
        float a0 = 0.f, a1 = 0.f, a2 = 0.f, a3 = 0.f;
        #pragma unroll
        for (int q = 0; q < 16; ++q) {
            float4 v = zr[q];
            a0 = fmaf(v.x, w1r[4*q],   a0);
            a1 = fmaf(v.y, w1r[4*q+1], a1);
            a2 = fmaf(v.z, w1r[4*q+2], a2);
            a3 = fmaf(v.w, w1r[4*q+3], a3);
        }
        float acc = (t >= 0) ? (bias + ((a0 + a1) + (a2 + a3))) : 0.f;
        xp0 = xp1; xp1 = xp2; xp2 = xp3; xp3 = acc;
        if (j >= 3) {
            float xc = cw.x*xp0 + cw.y*xp1 + cw.z*xp2 + cw.w*xp3 + cb;
            float xv = siluf(xc);
            unsigned short xb = f2bf(xv);
            xt[j-3][d] = xb;
            x_bf[((size_t)b * L_ + t0 + j - 3) * DI + d] = __builtin_bit_cast(__hip_bfloat16, xb);
        }
    }
    __syncthreads();

    // ---- phase B: x_dbl = x @ xproj^T (24 outputs per t); thread -> (t, 4-j group)
    if (tid < TT * 6) {
        int t = tid / 6, jg = tid % 6;
        int j0 = jg * 4;
        float a0 = 0.f, a1 = 0.f, a2 = 0.f, a3 = 0.f;
        #pragma unroll 8
        for (int k = 0; k < DI; k += 4) {
            unsigned long long xu = *(const unsigned long long*)&xt[t][k];
            float x0 = bf2f((unsigned short)(xu));
            float x1 = bf2f((unsigned short)(xu >> 16));
            float x2 = bf2f((unsigned short)(xu >> 32));
            float x3 = bf2f((unsigned short)(xu >> 48));
            float4 w0 = *(const float4*)&xw[k+0][j0];
            float4 w1v = *(const float4*)&xw[k+1][j0];
            float4 w2 = *(const float4*)&xw[k+2][j0];
            float4 w3 = *(const float4*)&xw[k+3][j0];
            a0 = fmaf(x0, w0.x, a0); a0 = fmaf(x1, w1v.x, a0); a0 = fmaf(x2, w2.x, a0); a0 = fmaf(x3, w3.x, a0);
            a1 = fmaf(x0, w0.y, a1); a1 = fmaf(x1, w1v.y, a1); a1 = fmaf(x2, w2.y, a1); a1 = fmaf(x3, w3.y, a1);
            a2 = fmaf(x0, w0.z, a2); a2 = fmaf(x1, w1v.z, a2); a2 = fmaf(x2, w2.z, a2); a2 = fmaf(x3, w3.z, a2);
            a3 = fmaf(x0, w0.w, a3); a3 = fmaf(x1, w1v.w, a3); a3 = fmaf(x2, w2.w, a3); a3 = fmaf(x3, w3.w, a3);
        }
        int tg = t0 + t;
        if (jg < 2) {
            float* dst = dtin + ((size_t)b * L_ + tg) * DR + j0;
            *(float4*)dst = make_float4(a0, a1, a2, a3);
        } else {
            float* dst = Bssm + ((size_t)b * L_ + tg) * DS + (j0 - 8);
            *(float4*)dst = make_float4(a0, a1, a2, a3);
        }
    }
}

// ---------------------------------------------------------------- K3a: per-chunk dt sums + dt materialization (bf16)
__global__ __launch_bounds__(256) void k3a_chunksums(
    const float* __restrict__ dtin, const float* __restrict__ dt_proj_w,
    const float* __restrict__ dt_proj_b, float* __restrict__ Dcs,
    __hip_bfloat16* __restrict__ dt_bf)
{
    int c = blockIdx.x, b = blockIdx.y, d = threadIdx.x;
    int t0 = c * TC;
    const float4* wp = (const float4*)(dt_proj_w + (size_t)d * DR);
    float4 wA = wp[0], wB = wp[1];
    float bias = dt_proj_b[d];
    const float* din = dtin + ((size_t)b * L_ + t0) * DR;
    __hip_bfloat16* dout = dt_bf + ((size_t)b * L_ + t0) * DI + d;
    float S = 0.f;
    for (int t = 0; t < TC; ++t) {
        const float4* dr = (const float4*)(din + (size_t)t * DR);
        float4 u = dr[0], v = dr[1];
        float r = bias + u.x*wA.x + u.y*wA.y + u.z*wA.z + u.w*wA.w
                       + v.x*wB.x + v.y*wB.y + v.z*wB.z + v.w*wB.w;
        float dt = softplusf(r);
        dout[(size_t)t * DI] = __float2bfloat16(dt);
        S += dt;
    }
    Dcs[((size_t)b * NC + c) * DI + d] = S;
}

// ---------------------------------------------------------------- K3a2: suffix sums of chunk dt-sums: Rsuf[b][c][d] = sum_{c'>c} Dcs
__global__ __launch_bounds__(256) void k3a2_suffix(
    const float* __restrict__ Dcs, float* __restrict__ Rsuf)
{
    int b = blockIdx.x, d = threadIdx.x;
    float R = 0.f;
    for (int c = NC - 1; c >= 0; --c) {
        Rsuf[((size_t)b * NC + c) * DI + d] = R;
        R += Dcs[((size_t)b * NC + c) * DI + d];
    }
}

// ---------------------------------------------------------------- K3b: LDS-free streaming suffix reduction
// lane map: wave w covers s in {2w, 2w+1}; lanes 0..31 -> s=2w, 32..63 -> s=2w+1; dh = lane&31
__global__ __launch_bounds__(512) void k3b_scan(
    const __hip_bfloat16* __restrict__ x_bf, const __hip_bfloat16* __restrict__ dt_bf,
    const float* __restrict__ Bssm, const float* __restrict__ A_log,
    const float* __restrict__ Rsuf, float* __restrict__ hpart)
{
    int c = blockIdx.x, dg = blockIdx.y, b = blockIdx.z;
    int tid = threadIdx.x;
    int dh = tid & 31;
    int s  = ((tid >> 6) << 1) | ((tid >> 5) & 1);
    int d  = dg * 32 + dh;

    float a = -__expf(A_log[d * DS + s]);
    float R = Rsuf[((size_t)b * NC + c) * DI + d];
    size_t hoff = (((size_t)c * B_ + b) * DS + s) * DI + d;   // [c][b][s][d]

    float H = 0.f;
    float S_run = R;
    if (!__all(a * R < THR)) {
        int t0 = c * TC;
        const __hip_bfloat16* xp = x_bf + ((size_t)b * L_ + t0) * DI + d;
        const __hip_bfloat16* dp = dt_bf + ((size_t)b * L_ + t0) * DI + d;
        const float* Bp = Bssm + ((size_t)b * L_ + t0) * DS + s;
        for (int j = TC - 4; j >= 0; j -= 4) {
            float x3 = __bfloat162float(xp[(j+3)*DI]);
            float x2 = __bfloat162float(xp[(j+2)*DI]);
            float x1 = __bfloat162float(xp[(j+1)*DI]);
            float x0 = __bfloat162float(xp[(j+0)*DI]);
            float d3 = __bfloat162float(dp[(j+3)*DI]);
            float d2 = __bfloat162float(dp[(j+2)*DI]);
            float d1 = __bfloat162float(dp[(j+1)*DI]);
            float d0 = __bfloat162float(dp[(j+0)*DI]);
            float B3 = Bp[(j+3)*DS];
            float B2 = Bp[(j+2)*DS];
            float B1 = Bp[(j+1)*DS];
            float B0 = Bp[(j+0)*DS];
            float e;
            e = __expf(a * S_run); H = fmaf(e * d3 * x3, B3, H); S_run += d3;
            e = __expf(a * S_run); H = fmaf(e * d2 * x2, B2, H); S_run += d2;
            e = __expf(a * S_run); H = fmaf(e * d1 * x1, B1, H); S_run += d1;
            e = __expf(a * S_run); H = fmaf(e * d0 * x0, B0, H); S_run += d0;
            if (__all(a * S_run < THR)) break;
        }
    }
    hpart[hoff] = H;
}

// ---------------------------------------------------------------- K3c: deterministic combine over chunks
__global__ __launch_bounds__(256) void k3c_comb(
    const float* __restrict__ hpart, float* __restrict__ h_last)
{
    int id = blockIdx.x * 256 + threadIdx.x;   // over B*DS*DI, layout ((b*DS+s)*DI+d)
    float acc = 0.f;
    for (int c = 0; c < NC; ++c) acc += hpart[(size_t)c * (B_ * DS * DI) + id];
    int d = id & (DI - 1);
    int s = (id >> 8) & (DS - 1);
    int b = id >> 12;
    h_last[((size_t)b * DI + d) * DS + s] = acc;
}

// ---------------------------------------------------------------- K4: the t = L-1 tail (C, y, z-gate, out_proj, LN, logit)
__global__ __launch_bounds__(256) void k4_final(
    const float* __restrict__ z, const float* __restrict__ emb_w,
    const float* __restrict__ emb_b, const float* __restrict__ in_proj_w,
    const float* __restrict__ conv_w, const float* __restrict__ conv_b,
    const float* __restrict__ x_proj_w, const float* __restrict__ D_skip,
    const float* __restrict__ out_proj_w, const float* __restrict__ norm_w,
    const float* __restrict__ norm_b, const float* __restrict__ cls_w,
    const float* __restrict__ cls_b, const float* __restrict__ W1,
    const float* __restrict__ b1, const float* __restrict__ h_last,
    float* __restrict__ out)
{
    __shared__ float zl[4][64];
    __shared__ float xlast[DI];
    __shared__ float xemb[DM];
    __shared__ float Cl[DS];
    __shared__ float ylds[DI];
    __shared__ float olds[DM];
    int b = blockIdx.x, tid = threadIdx.x;
    {
        int r = tid >> 6, k = tid & 63;
        zl[r][k] = z[((size_t)b * L_ + (L_ - 4 + r)) * LAT + k];
    }
    __syncthreads();
    {   // x at t = L-1 (conv over last 4 x_pre)
        int d = tid;
        const float* wr = W1 + d * LAT;
        float xp[4];
        #pragma unroll
        for (int r = 0; r < 4; ++r) {
            float acc = b1[d];
            for (int k = 0; k < LAT; ++k) acc += zl[r][k] * wr[k];
            xp[r] = acc;
        }
        float4 cw = *(const float4*)(conv_w + d * 4);
        float xc = cw.x*xp[0] + cw.y*xp[1] + cw.z*xp[2] + cw.w*xp[3] + conv_b[d];
        xlast[d] = siluf(xc);
    }
    __syncthreads();
    if (tid < DS) {   // C at L-1
        float acc = 0.f;
        const float* wr = x_proj_w + (size_t)(DR + DS + tid) * DI;
        for (int k = 0; k < DI; ++k) acc += xlast[k] * wr[k];
        Cl[tid] = acc;
    }
    if (tid >= 64 && tid < 64 + DM) {   // x_emb at L-1 (for z-branch)
        int m = tid - 64;
        float acc = emb_b[m];
        const float* wr = emb_w + (size_t)m * LAT;
        for (int k = 0; k < LAT; ++k) acc += zl[3][k] * wr[k];
        xemb[m] = acc;
    }
    __syncthreads();
    {   // y = (h.C) + x*D_skip, gated by silu(z-branch)
        int d = tid;
        const float* hr = h_last + ((size_t)b * DI + d) * DS;
        float hs = 0.f;
        #pragma unroll
        for (int si = 0; si < DS; ++si) hs += hr[si] * Cl[si];
        float y = hs + xlast[d] * D_skip[d];
        float zbv = 0.f;
        const float* wr = in_proj_w + (size_t)(DI + d) * DM;
        for (int m = 0; m < DM; ++m) zbv += xemb[m] * wr[m];
        y *= siluf(zbv);
        ylds[d] = y;
    }
    __syncthreads();
    if (tid < DM) {   // out_proj
        float acc = 0.f;
        const float* wr = out_proj_w + (size_t)tid * DI;
        for (int k = 0; k < DI; ++k) acc += ylds[k] * wr[k];
        olds[tid] = acc;
    }
    __syncthreads();
    if (tid < 64) {   // LayerNorm + classifier (one wave)
        float v0 = olds[tid], v1 = olds[tid + 64];
        float sum = v0 + v1;
        #pragma unroll
        for (int off = 32; off > 0; off >>= 1) sum += __shfl_down(sum, off);
        float mu = __shfl(sum, 0) * (1.0f / 128.0f);
        float dv0 = v0 - mu, dv1 = v1 - mu;
        float vs = dv0 * dv0 + dv1 * dv1;
        #pragma unroll
        for (int off = 32; off > 0; off >>= 1) vs += __shfl_down(vs, off);
        float var = __shfl(vs, 0) * (1.0f / 128.0f);
        float rstd = rsqrtf(var + 1e-5f);
        float xn0 = dv0 * rstd * norm_w[tid] + norm_b[tid];
        float xn1 = dv1 * rstd * norm_w[tid + 64] + norm_b[tid + 64];
        float lg = xn0 * cls_w[tid] + xn1 * cls_w[tid + 64];
        #pragma unroll
        for (int off = 32; off > 0; off >>= 1) lg += __shfl_down(lg, off);
        if (tid == 0) out[b] = lg + cls_b[0];
    }
}

// ---------------------------------------------------------------- launch
extern "C" void kernel_launch(void* const* d_in, const int* in_sizes, int n_in,
                              void* d_out, int out_size, void* d_ws, size_t ws_size,
                              hipStream_t stream) {
    (void)in_sizes; (void)n_in; (void)out_size;
    const float* z         = (const float*)d_in[0];
    const float* emb_w     = (const float*)d_in[1];
    const float* emb_b     = (const float*)d_in[2];
    const float* in_proj_w = (const float*)d_in[3];
    const float* conv_w    = (const float*)d_in[4];
    const float* conv_b    = (const float*)d_in[5];
    const float* x_proj_w  = (const float*)d_in[6];
    const float* dt_proj_w = (const float*)d_in[7];
    const float* dt_proj_b = (const float*)d_in[8];
    const float* A_log     = (const float*)d_in[9];
    const float* D_skip    = (const float*)d_in[10];
    const float* out_proj_w= (const float*)d_in[11];
    const float* norm_w    = (const float*)d_in[12];
    const float* norm_b    = (const float*)d_in[13];
    const float* cls_w     = (const float*)d_in[14];
    const float* cls_b     = (const float*)d_in[15];
    float* out = (float*)d_out;

    float* ws    = (float*)d_ws;
    float* W1    = ws;                       // 16384
    float* b1    = W1 + 16384;               // 256
    float* dtin  = b1 + 256;                 // 16*3600*8   = 460800
    float* Bssm  = dtin + 460800;            // 16*3600*16  = 921600
    float* Dcs   = Bssm + 921600;            // 16*36*256   = 147456
    float* Rsuf  = Dcs + 147456;             // 16*36*256   = 147456
    float* hpart = Rsuf + 147456;            // 36*16*16*256= 2359296
    float* hlast = hpart + 2359296;          // 16*256*16   = 65536
    float* fend  = hlast + 65536;
    __hip_bfloat16* x_bf  = (__hip_bfloat16*)fend;            // 16*3600*256 bf16
    __hip_bfloat16* dt_bf = x_bf + (size_t)B_ * L_ * DI;      // 16*3600*256 bf16
    size_t needed = ((size_t)(16384 + 256 + 460800 + 921600 + 147456 + 147456 + 2359296 + 65536)) * 4
                  + (size_t)B_ * L_ * DI * 2 * 2;
    if (ws_size < needed) return;

    k0_combine   <<<dim3(DI),        dim3(LAT), 0, stream>>>(in_proj_w, emb_w, emb_b, W1, b1);
    k1_front     <<<dim3(NT, B_),    dim3(256), 0, stream>>>(z, conv_w, conv_b, x_proj_w, W1, b1, dtin, Bssm, x_bf);
    k3a_chunksums<<<dim3(NC, B_),    dim3(256), 0, stream>>>(dtin, dt_proj_w, dt_proj_b, Dcs, dt_bf);
    k3a2_suffix  <<<dim3(B_),        dim3(256), 0, stream>>>(Dcs, Rsuf);
    k3b_scan     <<<dim3(NC, 8, B_), dim3(512), 0, stream>>>(x_bf, dt_bf, Bssm, A_log, Rsuf, hpart);
    k3c_comb     <<<dim3(256),       dim3(256), 0, stream>>>(hpart, hlast);
    k4_final     <<<dim3(B_),        dim3(256), 0, stream>>>(z, emb_w, emb_b, in_proj_w, conv_w, conv_b,
                                                             x_proj_w, D_skip, out_proj_w, norm_w, norm_b,
                                                             cls_w, cls_b, W1, b1, hlast, out);
}

// Round 2
// 130.287 us; speedup vs baseline: 1.9481x; 1.3788x over previous
//
#include <hip/hip_runtime.h>
#include <hip/hip_bf16.h>
#include <math.h>

#define B_  16
#define L_  3600
#define LAT 64
#define DM  128
#define DI  256
#define DS  16
#define DR  8

#define TT  45    // K1 time-tile (48 rows incl. 3-row conv history = 3 MFMA m-tiles)
#define NT  80    // 3600/45
#define TC  100   // scan chunk length
#define NC  36    // 3600/100
#define THR (-20.0f)   // exp(a*S) < exp(-20) ~ 2e-9 -> negligible

typedef __bf16 v8bf __attribute__((ext_vector_type(8)));
typedef float  v4f  __attribute__((ext_vector_type(4)));
typedef unsigned short v8us __attribute__((ext_vector_type(8)));

#define MFMA16(A, Bf, C) __builtin_amdgcn_mfma_f32_16x16x32_bf16((A), (Bf), (C), 0, 0, 0)

__device__ __forceinline__ float siluf(float v) {
    return v * __builtin_amdgcn_rcpf(1.0f + __expf(-v));
}
__device__ __forceinline__ float softplusf(float v) {
    float r = __logf(1.0f + __expf(v));
    return (v > 15.0f) ? v : r;
}
__device__ __forceinline__ float bf2f(unsigned short u) {
    unsigned int x = ((unsigned int)u) << 16;
    return __builtin_bit_cast(float, x);
}
__device__ __forceinline__ unsigned short f2bf(float f) {
    __hip_bfloat16 h = __float2bfloat16(f);
    return __builtin_bit_cast(unsigned short, h);
}

// ---------------------------------------------------------------- K0: W1 = in_proj_x @ emb_w, b1 = in_proj_x @ emb_b
__global__ __launch_bounds__(64) void k0_combine(
    const float* __restrict__ in_proj_w, const float* __restrict__ emb_w,
    const float* __restrict__ emb_b, float* __restrict__ W1, float* __restrict__ b1)
{
    int d = blockIdx.x, k = threadIdx.x;
    const float* row = in_proj_w + (size_t)d * DM;
    float acc = 0.f;
    for (int m = 0; m < DM; ++m) acc += row[m] * emb_w[m * LAT + k];
    W1[d * LAT + k] = acc;
    if (k == 0) {
        float ab = 0.f;
        for (int m = 0; m < DM; ++m) ab += row[m] * emb_b[m];
        b1[d] = ab;
    }
}

// ---------------------------------------------------------------- K1: MFMA front-end
// phase A: xpre = z @ W1^T via hi/lo bf16 split MFMA (fp32-equivalent accuracy)
// conv+silu per channel in registers -> x_bf (global) and xt (LDS bf16)
// phase B: x_dbl = xt @ x_proj[0:24]^T via MFMA (weights hi/lo split)
__global__ __launch_bounds__(256, 2) void k1_front(
    const float* __restrict__ z, const float* __restrict__ conv_w,
    const float* __restrict__ conv_b, const float* __restrict__ x_proj_w,
    const float* __restrict__ W1, const float* __restrict__ b1,
    float* __restrict__ dtin, float* __restrict__ Bssm,
    __hip_bfloat16* __restrict__ x_bf)
{
    // region 1: xpre [48][258] f32 (49,536B); later reused as xt bf16 [48][512 u16, swizzled]
    __shared__ float xpre[48 * 258];
    // region 2: zt hi/lo bf16 (2*3072 u16); later reused as xw hi/lo bf16 (2*6144 u16)
    __shared__ unsigned short uB[12288];

    int b = blockIdx.y, tile = blockIdx.x;
    int t0 = tile * TT;
    int t0m3 = t0 - 3;
    int tid = threadIdx.x;
    int lane = tid & 63, wid = tid >> 6;
    int l15 = lane & 15, l4 = lane >> 4;

    // per-thread conv params (channel d = tid)
    float4 cw = *(const float4*)(conv_w + tid * 4);
    float cb = conv_b[tid];
    float bias = b1[tid];

    // ---- B-frags for phase A from W1 (hi/lo), weights-stationary in registers
    // B[k][d] = W1[d][k]; frag: col d = d0w+nt*16+l15, k = kb*32 + l4*8 .. +7
    v8bf wh[4][2], wl[4][2];
    {
        int d0w = wid * 64;
        #pragma unroll
        for (int nt = 0; nt < 4; ++nt) {
            int dr = d0w + nt * 16 + l15;
            const float* wrow = W1 + (size_t)dr * LAT;
            #pragma unroll
            for (int kb = 0; kb < 2; ++kb) {
                int k0 = kb * 32 + l4 * 8;
                float4 u = *(const float4*)(wrow + k0);
                float4 v = *(const float4*)(wrow + k0 + 4);
                float f[8] = {u.x, u.y, u.z, u.w, v.x, v.y, v.z, v.w};
                v8us hh, ll;
                #pragma unroll
                for (int i = 0; i < 8; ++i) {
                    unsigned short h = f2bf(f[i]);
                    hh[i] = h;
                    ll[i] = f2bf(f[i] - bf2f(h));
                }
                wh[nt][kb] = __builtin_bit_cast(v8bf, hh);
                wl[nt][kb] = __builtin_bit_cast(v8bf, ll);
            }
        }
    }

    // ---- stage z tile (48 rows incl history) as hi/lo bf16, XOR-swizzled rows
    {
        const float* zb = z + (size_t)b * L_ * LAT;
        for (int i = tid; i < 48 * 8; i += 256) {   // (row, 8-elem slot)
            int r = i >> 3, s = i & 7;
            int tg = t0m3 + r;
            float f[8];
            if (tg >= 0) {
                float4 u = *(const float4*)(zb + (size_t)tg * LAT + s * 8);
                float4 v = *(const float4*)(zb + (size_t)tg * LAT + s * 8 + 4);
                f[0]=u.x; f[1]=u.y; f[2]=u.z; f[3]=u.w; f[4]=v.x; f[5]=v.y; f[6]=v.z; f[7]=v.w;
            } else {
                #pragma unroll
                for (int q = 0; q < 8; ++q) f[q] = 0.f;
            }
            v8us hh, ll;
            #pragma unroll
            for (int q = 0; q < 8; ++q) {
                unsigned short h = f2bf(f[q]);
                hh[q] = h;
                ll[q] = f2bf(f[q] - bf2f(h));
            }
            int idx = r * 64 + ((s * 8) ^ ((r & 7) << 3));   // u16 units, 16B-aligned slots
            *(v8us*)&uB[idx] = hh;
            *(v8us*)&uB[3072 + idx] = ll;
        }
    }
    __syncthreads();

    // ---- phase A MFMA: 3 m-tiles x 4 n-tiles, K=64, 6 MFMA per tile (hi/lo cross terms)
    {
        int d0w = wid * 64;
        #pragma unroll
        for (int mt = 0; mt < 3; ++mt) {
            int r = mt * 16 + l15;
            int sw = (r & 7) << 3;
            int kb0 = l4 * 8;
            v8bf ah0 = __builtin_bit_cast(v8bf, *(const v8us*)&uB[r * 64 + (kb0 ^ sw)]);
            v8bf ah1 = __builtin_bit_cast(v8bf, *(const v8us*)&uB[r * 64 + ((32 + kb0) ^ sw)]);
            v8bf al0 = __builtin_bit_cast(v8bf, *(const v8us*)&uB[3072 + r * 64 + (kb0 ^ sw)]);
            v8bf al1 = __builtin_bit_cast(v8bf, *(const v8us*)&uB[3072 + r * 64 + ((32 + kb0) ^ sw)]);
            int rr = mt * 16 + l4 * 4;
            #pragma unroll
            for (int nt = 0; nt < 4; ++nt) {
                v4f acc = {0.f, 0.f, 0.f, 0.f};
                acc = MFMA16(ah0, wh[nt][0], acc);
                acc = MFMA16(ah1, wh[nt][1], acc);
                acc = MFMA16(ah0, wl[nt][0], acc);
                acc = MFMA16(ah1, wl[nt][1], acc);
                acc = MFMA16(al0, wh[nt][0], acc);
                acc = MFMA16(al1, wh[nt][1], acc);
                int cc = d0w + nt * 16 + l15;
                // D: col=lane&15, row=(lane>>4)*4+reg
                xpre[(rr + 0) * 258 + cc] = acc[0];
                xpre[(rr + 1) * 258 + cc] = acc[1];
                xpre[(rr + 2) * 258 + cc] = acc[2];
                xpre[(rr + 3) * 258 + cc] = acc[3];
            }
        }
    }

    // issue x_proj global loads early (latency hides under conv)
    float4 xwreg[6];
    {
        #pragma unroll
        for (int p = 0; p < 3; ++p) {
            int i = tid + p * 256;            // 768 (j, 8-elem slot) pairs
            int j = i >> 5, s = i & 31;
            const float* src = x_proj_w + (size_t)j * DI + s * 8;
            xwreg[2 * p]     = *(const float4*)(src);
            xwreg[2 * p + 1] = *(const float4*)(src + 4);
        }
    }
    __syncthreads();

    // ---- conv + silu per channel column (d = tid); keep x in registers
    float xr[TT];
    {
        int d = tid;
        float p0 = xpre[0 * 258 + d] + ((t0m3 + 0 >= 0) ? bias : 0.f);
        float p1 = xpre[1 * 258 + d] + ((t0m3 + 1 >= 0) ? bias : 0.f);
        float p2 = xpre[2 * 258 + d] + ((t0m3 + 2 >= 0) ? bias : 0.f);
        #pragma unroll
        for (int r = 3; r < 48; ++r) {
            float cur = xpre[r * 258 + d] + bias;
            float xc = cw.x * p0 + cw.y * p1 + cw.z * p2 + cw.w * cur + cb;
            xr[r - 3] = siluf(xc);
            p0 = p1; p1 = p2; p2 = cur;
        }
        // coalesced bf16 stores of x
        __hip_bfloat16* xb = x_bf + ((size_t)b * L_ + t0) * DI + d;
        #pragma unroll
        for (int t = 0; t < TT; ++t)
            xb[(size_t)t * DI] = __float2bfloat16(xr[t]);
    }
    __syncthreads();   // xpre dead, zt dead

    // ---- write xt bf16 (swizzled, over xpre space); stage xw hi/lo (over zt space)
    unsigned short* xt16 = (unsigned short*)xpre;   // [48][512 u16], slot-swizzled
    {
        int d = tid;
        #pragma unroll
        for (int t = 0; t < TT; ++t)
            xt16[t * 512 + (d ^ ((t & 7) << 3))] = f2bf(xr[t]);
        // zero pad rows 45..47 (read by m-tile 2, outputs discarded)
        #pragma unroll
        for (int t = TT; t < 48; ++t)
            xt16[t * 512 + (d ^ ((t & 7) << 3))] = 0;
        #pragma unroll
        for (int p = 0; p < 3; ++p) {
            int i = tid + p * 256;
            int j = i >> 5, s = i & 31;
            float4 u = xwreg[2 * p], v = xwreg[2 * p + 1];
            float f[8] = {u.x, u.y, u.z, u.w, v.x, v.y, v.z, v.w};
            v8us hh, ll;
            #pragma unroll
            for (int q = 0; q < 8; ++q) {
                unsigned short h = f2bf(f[q]);
                hh[q] = h;
                ll[q] = f2bf(f[q] - bf2f(h));
            }
            int idx = j * 256 + ((s * 8) ^ ((j & 7) << 3));
            *(v8us*)&uB[idx] = hh;
            *(v8us*)&uB[6144 + idx] = ll;
        }
    }
    __syncthreads();

    // ---- phase B MFMA: x_dbl[t][j] = sum_k xt[t][k] * x_proj_w[j][k], j = 0..23
    if (wid < 3) {
        int mt = wid;
        int rA = mt * 16 + l15;
        int swA = (rA & 7) << 3;
        int jc0 = l15;
        int jc1 = 16 + l15; if (jc1 > 23) jc1 = 23;   // clamp (outputs >=24 discarded)
        v4f acc0 = {0.f, 0.f, 0.f, 0.f}, acc1 = {0.f, 0.f, 0.f, 0.f};
        #pragma unroll
        for (int kb = 0; kb < 8; ++kb) {
            int k0 = kb * 32 + l4 * 8;
            v8bf xa  = __builtin_bit_cast(v8bf, *(const v8us*)&xt16[rA * 512 + (k0 ^ swA)]);
            int s0 = k0 ^ ((jc0 & 7) << 3);
            int s1 = k0 ^ ((jc1 & 7) << 3);
            v8bf b0h = __builtin_bit_cast(v8bf, *(const v8us*)&uB[jc0 * 256 + s0]);
            v8bf b0l = __builtin_bit_cast(v8bf, *(const v8us*)&uB[6144 + jc0 * 256 + s0]);
            v8bf b1h = __builtin_bit_cast(v8bf, *(const v8us*)&uB[jc1 * 256 + s1]);
            v8bf b1l = __builtin_bit_cast(v8bf, *(const v8us*)&uB[6144 + jc1 * 256 + s1]);
            acc0 = MFMA16(xa, b0h, acc0);
            acc0 = MFMA16(xa, b0l, acc0);
            acc1 = MFMA16(xa, b1h, acc1);
            acc1 = MFMA16(xa, b1l, acc1);
        }
        int rr = mt * 16 + l4 * 4;
        #pragma unroll
        for (int reg = 0; reg < 4; ++reg) {
            int t = rr + reg;
            if (t < TT) {
                size_t tg = (size_t)b * L_ + (t0 + t);
                float v0 = acc0[reg], v1 = acc1[reg];
                if (l15 < 8) {
                    dtin[tg * DR + l15] = v0;          // dt_in cols 0..7
                    Bssm[tg * DS + 8 + l15] = v1;      // B cols 8..15 (j = 16..23)
                } else {
                    Bssm[tg * DS + (l15 - 8)] = v0;    // B cols 0..7 (j = 8..15)
                }
            }
        }
    }
}

// ---------------------------------------------------------------- K3a: per-chunk dt sums + dt materialization (bf16)
__global__ __launch_bounds__(256) void k3a_chunksums(
    const float* __restrict__ dtin, const float* __restrict__ dt_proj_w,
    const float* __restrict__ dt_proj_b, float* __restrict__ Dcs,
    __hip_bfloat16* __restrict__ dt_bf)
{
    int c = blockIdx.x, b = blockIdx.y, d = threadIdx.x;
    int t0 = c * TC;
    const float4* wp = (const float4*)(dt_proj_w + (size_t)d * DR);
    float4 wA = wp[0], wB = wp[1];
    float bias = dt_proj_b[d];
    const float* din = dtin + ((size_t)b * L_ + t0) * DR;
    __hip_bfloat16* dout = dt_bf + ((size_t)b * L_ + t0) * DI + d;
    float S = 0.f;
    for (int t = 0; t < TC; ++t) {
        const float4* dr = (const float4*)(din + (size_t)t * DR);
        float4 u = dr[0], v = dr[1];
        float r = bias + u.x*wA.x + u.y*wA.y + u.z*wA.z + u.w*wA.w
                       + v.x*wB.x + v.y*wB.y + v.z*wB.z + v.w*wB.w;
        float dt = softplusf(r);
        dout[(size_t)t * DI] = __float2bfloat16(dt);
        S += dt;
    }
    Dcs[((size_t)b * NC + c) * DI + d] = S;
}

// ---------------------------------------------------------------- K3a2: suffix sums of chunk dt-sums
__global__ __launch_bounds__(256) void k3a2_suffix(
    const float* __restrict__ Dcs, float* __restrict__ Rsuf)
{
    int b = blockIdx.x, d = threadIdx.x;
    float R = 0.f;
    for (int c = NC - 1; c >= 0; --c) {
        Rsuf[((size_t)b * NC + c) * DI + d] = R;
        R += Dcs[((size_t)b * NC + c) * DI + d];
    }
}

// ---------------------------------------------------------------- K3b: LDS-free streaming suffix reduction
__global__ __launch_bounds__(512) void k3b_scan(
    const __hip_bfloat16* __restrict__ x_bf, const __hip_bfloat16* __restrict__ dt_bf,
    const float* __restrict__ Bssm, const float* __restrict__ A_log,
    const float* __restrict__ Rsuf, float* __restrict__ hpart)
{
    int c = blockIdx.x, dg = blockIdx.y, b = blockIdx.z;
    int tid = threadIdx.x;
    int dh = tid & 31;
    int s  = ((tid >> 6) << 1) | ((tid >> 5) & 1);
    int d  = dg * 32 + dh;

    float a = -__expf(A_log[d * DS + s]);
    float R = Rsuf[((size_t)b * NC + c) * DI + d];
    size_t hoff = (((size_t)c * B_ + b) * DS + s) * DI + d;   // [c][b][s][d]

    float H = 0.f;
    float S_run = R;
    if (!__all(a * R < THR)) {
        int t0 = c * TC;
        const __hip_bfloat16* xp = x_bf + ((size_t)b * L_ + t0) * DI + d;
        const __hip_bfloat16* dp = dt_bf + ((size_t)b * L_ + t0) * DI + d;
        const float* Bp = Bssm + ((size_t)b * L_ + t0) * DS + s;
        for (int j = TC - 4; j >= 0; j -= 4) {
            float x3 = __bfloat162float(xp[(j+3)*DI]);
            float x2 = __bfloat162float(xp[(j+2)*DI]);
            float x1 = __bfloat162float(xp[(j+1)*DI]);
            float x0 = __bfloat162float(xp[(j+0)*DI]);
            float d3 = __bfloat162float(dp[(j+3)*DI]);
            float d2 = __bfloat162float(dp[(j+2)*DI]);
            float d1 = __bfloat162float(dp[(j+1)*DI]);
            float d0 = __bfloat162float(dp[(j+0)*DI]);
            float B3 = Bp[(j+3)*DS];
            float B2 = Bp[(j+2)*DS];
            float B1 = Bp[(j+1)*DS];
            float B0 = Bp[(j+0)*DS];
            float e;
            e = __expf(a * S_run); H = fmaf(e * d3 * x3, B3, H); S_run += d3;
            e = __expf(a * S_run); H = fmaf(e * d2 * x2, B2, H); S_run += d2;
            e = __expf(a * S_run); H = fmaf(e * d1 * x1, B1, H); S_run += d1;
            e = __expf(a * S_run); H = fmaf(e * d0 * x0, B0, H); S_run += d0;
            if (__all(a * S_run < THR)) break;
        }
    }
    hpart[hoff] = H;
}

// ---------------------------------------------------------------- K3c: deterministic combine over chunks
__global__ __launch_bounds__(256) void k3c_comb(
    const float* __restrict__ hpart, float* __restrict__ h_last)
{
    int id = blockIdx.x * 256 + threadIdx.x;   // over B*DS*DI, layout ((b*DS+s)*DI+d)
    float acc = 0.f;
    for (int c = 0; c < NC; ++c) acc += hpart[(size_t)c * (B_ * DS * DI) + id];
    int d = id & (DI - 1);
    int s = (id >> 8) & (DS - 1);
    int b = id >> 12;
    h_last[((size_t)b * DI + d) * DS + s] = acc;
}

// ---------------------------------------------------------------- K4: the t = L-1 tail
__global__ __launch_bounds__(256) void k4_final(
    const float* __restrict__ z, const float* __restrict__ emb_w,
    const float* __restrict__ emb_b, const float* __restrict__ in_proj_w,
    const float* __restrict__ conv_w, const float* __restrict__ conv_b,
    const float* __restrict__ x_proj_w, const float* __restrict__ D_skip,
    const float* __restrict__ out_proj_w, const float* __restrict__ norm_w,
    const float* __restrict__ norm_b, const float* __restrict__ cls_w,
    const float* __restrict__ cls_b, const float* __restrict__ W1,
    const float* __restrict__ b1, const float* __restrict__ h_last,
    float* __restrict__ out)
{
    __shared__ float zl[4][64];
    __shared__ float xlast[DI];
    __shared__ float xemb[DM];
    __shared__ float Cl[DS];
    __shared__ float ylds[DI];
    __shared__ float olds[DM];
    int b = blockIdx.x, tid = threadIdx.x;
    {
        int r = tid >> 6, k = tid & 63;
        zl[r][k] = z[((size_t)b * L_ + (L_ - 4 + r)) * LAT + k];
    }
    __syncthreads();
    {   // x at t = L-1 (conv over last 4 x_pre)
        int d = tid;
        const float* wr = W1 + d * LAT;
        float xp[4];
        #pragma unroll
        for (int r = 0; r < 4; ++r) {
            float acc = b1[d];
            for (int k = 0; k < LAT; ++k) acc += zl[r][k] * wr[k];
            xp[r] = acc;
        }
        float4 cwv = *(const float4*)(conv_w + d * 4);
        float xc = cwv.x*xp[0] + cwv.y*xp[1] + cwv.z*xp[2] + cwv.w*xp[3] + conv_b[d];
        xlast[d] = siluf(xc);
    }
    __syncthreads();
    if (tid < DS) {   // C at L-1
        float acc = 0.f;
        const float* wr = x_proj_w + (size_t)(DR + DS + tid) * DI;
        for (int k = 0; k < DI; ++k) acc += xlast[k] * wr[k];
        Cl[tid] = acc;
    }
    if (tid >= 64 && tid < 64 + DM) {   // x_emb at L-1 (for z-branch)
        int m = tid - 64;
        float acc = emb_b[m];
        const float* wr = emb_w + (size_t)m * LAT;
        for (int k = 0; k < LAT; ++k) acc += zl[3][k] * wr[k];
        xemb[m] = acc;
    }
    __syncthreads();
    {   // y = (h.C) + x*D_skip, gated by silu(z-branch)
        int d = tid;
        const float* hr = h_last + ((size_t)b * DI + d) * DS;
        float hs = 0.f;
        #pragma unroll
        for (int si = 0; si < DS; ++si) hs += hr[si] * Cl[si];
        float y = hs + xlast[d] * D_skip[d];
        float zbv = 0.f;
        const float* wr = in_proj_w + (size_t)(DI + d) * DM;
        for (int m = 0; m < DM; ++m) zbv += xemb[m] * wr[m];
        y *= siluf(zbv);
        ylds[d] = y;
    }
    __syncthreads();
    if (tid < DM) {   // out_proj
        float acc = 0.f;
        const float* wr = out_proj_w + (size_t)tid * DI;
        for (int k = 0; k < DI; ++k) acc += ylds[k] * wr[k];
        olds[tid] = acc;
    }
    __syncthreads();
    if (tid < 64) {   // LayerNorm + classifier (one wave)
        float v0 = olds[tid], v1 = olds[tid + 64];
        float sum = v0 + v1;
        #pragma unroll
        for (int off = 32; off > 0; off >>= 1) sum += __shfl_down(sum, off);
        float mu = __shfl(sum, 0) * (1.0f / 128.0f);
        float dv0 = v0 - mu, dv1 = v1 - mu;
        float vs = dv0 * dv0 + dv1 * dv1;
        #pragma unroll
        for (int off = 32; off > 0; off >>= 1) vs += __shfl_down(vs, off);
        float var = __shfl(vs, 0) * (1.0f / 128.0f);
        float rstd = rsqrtf(var + 1e-5f);
        float xn0 = dv0 * rstd * norm_w[tid] + norm_b[tid];
        float xn1 = dv1 * rstd * norm_w[tid + 64] + norm_b[tid + 64];
        float lg = xn0 * cls_w[tid] + xn1 * cls_w[tid + 64];
        #pragma unroll
        for (int off = 32; off > 0; off >>= 1) lg += __shfl_down(lg, off);
        if (tid == 0) out[b] = lg + cls_b[0];
    }
}

// ---------------------------------------------------------------- launch
extern "C" void kernel_launch(void* const* d_in, const int* in_sizes, int n_in,
                              void* d_out, int out_size, void* d_ws, size_t ws_size,
                              hipStream_t stream) {
    (void)in_sizes; (void)n_in; (void)out_size;
    const float* z         = (const float*)d_in[0];
    const float* emb_w     = (const float*)d_in[1];
    const float* emb_b     = (const float*)d_in[2];
    const float* in_proj_w = (const float*)d_in[3];
    const float* conv_w    = (const float*)d_in[4];
    const float* conv_b    = (const float*)d_in[5];
    const float* x_proj_w  = (const float*)d_in[6];
    const float* dt_proj_w = (const float*)d_in[7];
    const float* dt_proj_b = (const float*)d_in[8];
    const float* A_log     = (const float*)d_in[9];
    const float* D_skip    = (const float*)d_in[10];
    const float* out_proj_w= (const float*)d_in[11];
    const float* norm_w    = (const float*)d_in[12];
    const float* norm_b    = (const float*)d_in[13];
    const float* cls_w     = (const float*)d_in[14];
    const float* cls_b     = (const float*)d_in[15];
    float* out = (float*)d_out;

    float* ws    = (float*)d_ws;
    float* W1    = ws;                       // 16384
    float* b1    = W1 + 16384;               // 256
    float* dtin  = b1 + 256;                 // 16*3600*8   = 460800
    float* Bssm  = dtin + 460800;            // 16*3600*16  = 921600
    float* Dcs   = Bssm + 921600;            // 16*36*256   = 147456
    float* Rsuf  = Dcs + 147456;             // 16*36*256   = 147456
    float* hpart = Rsuf + 147456;            // 36*16*16*256= 2359296
    float* hlast = hpart + 2359296;          // 16*256*16   = 65536
    float* fend  = hlast + 65536;
    __hip_bfloat16* x_bf  = (__hip_bfloat16*)fend;            // 16*3600*256 bf16
    __hip_bfloat16* dt_bf = x_bf + (size_t)B_ * L_ * DI;      // 16*3600*256 bf16
    size_t needed = ((size_t)(16384 + 256 + 460800 + 921600 + 147456 + 147456 + 2359296 + 65536)) * 4
                  + (size_t)B_ * L_ * DI * 2 * 2;
    if (ws_size < needed) return;

    k0_combine   <<<dim3(DI),        dim3(LAT), 0, stream>>>(in_proj_w, emb_w, emb_b, W1, b1);
    k1_front     <<<dim3(NT, B_),    dim3(256), 0, stream>>>(z, conv_w, conv_b, x_proj_w, W1, b1, dtin, Bssm, x_bf);
    k3a_chunksums<<<dim3(NC, B_),    dim3(256), 0, stream>>>(dtin, dt_proj_w, dt_proj_b, Dcs, dt_bf);
    k3a2_suffix  <<<dim3(B_),        dim3(256), 0, stream>>>(Dcs, Rsuf);
    k3b_scan     <<<dim3(NC, 8, B_), dim3(512), 0, stream>>>(x_bf, dt_bf, Bssm, A_log, Rsuf, hpart);
    k3c_comb     <<<dim3(256),       dim3(256), 0, stream>>>(hpart, hlast);
    k4_final     <<<dim3(B_),        dim3(256), 0, stream>>>(z, emb_w, emb_b, in_proj_w, conv_w, conv_b,
                                                             x_proj_w, D_skip, out_proj_w, norm_w, norm_b,
                                                             cls_w, cls_b, W1, b1, hlast, out);
}

// Round 3
// 121.602 us; speedup vs baseline: 2.0872x; 1.0714x over previous
//
#include <hip/hip_runtime.h>
#include <hip/hip_bf16.h>
#include <math.h>

#define B_  16
#define L_  3600
#define LAT 64
#define DM  128
#define DI  256
#define DS  16
#define DR  8

#define TT  45    // K1 time-tile == scan chunk length
#define NT  80    // 3600/45 tiles == chunks
#define NC  80
#define TC  45
#define THR (-20.0f)   // exp(a*S) < exp(-20) ~ 2e-9 -> negligible

typedef __bf16 v8bf __attribute__((ext_vector_type(8)));
typedef float  v4f  __attribute__((ext_vector_type(4)));
typedef unsigned short v8us __attribute__((ext_vector_type(8)));

#define MFMA16(A, Bf, C) __builtin_amdgcn_mfma_f32_16x16x32_bf16((A), (Bf), (C), 0, 0, 0)

__device__ __forceinline__ float siluf(float v) {
    return v * __builtin_amdgcn_rcpf(1.0f + __expf(-v));
}
__device__ __forceinline__ float softplusf(float v) {
    float r = __logf(1.0f + __expf(v));
    return (v > 15.0f) ? v : r;
}
__device__ __forceinline__ float bf2f(unsigned short u) {
    unsigned int x = ((unsigned int)u) << 16;
    return __builtin_bit_cast(float, x);
}
__device__ __forceinline__ unsigned short f2bf(float f) {
    __hip_bfloat16 h = __float2bfloat16(f);
    return __builtin_bit_cast(unsigned short, h);
}

// ---------------------------------------------------------------- K0: W1 = in_proj_x @ emb_w (+ hi/lo bf16), b1; pre-swizzled x_proj hi/lo
__global__ __launch_bounds__(64) void k0_combine(
    const float* __restrict__ in_proj_w, const float* __restrict__ emb_w,
    const float* __restrict__ emb_b, const float* __restrict__ x_proj_w,
    float* __restrict__ W1, float* __restrict__ b1,
    unsigned short* __restrict__ W1h, unsigned short* __restrict__ W1l,
    unsigned short* __restrict__ xwh, unsigned short* __restrict__ xwl)
{
    int blk = blockIdx.x, k = threadIdx.x;
    if (blk < DI) {
        int d = blk;
        const float* row = in_proj_w + (size_t)d * DM;
        float acc = 0.f;
        for (int m = 0; m < DM; ++m) acc += row[m] * emb_w[m * LAT + k];
        W1[d * LAT + k] = acc;
        unsigned short h = f2bf(acc);
        W1h[d * LAT + k] = h;
        W1l[d * LAT + k] = f2bf(acc - bf2f(h));
        if (k == 0) {
            float ab = 0.f;
            for (int m = 0; m < DM; ++m) ab += row[m] * emb_b[m];
            b1[d] = ab;
        }
    } else {
        int j = blk - DI;   // 0..23
        int sw = (j & 7) << 3;
        #pragma unroll
        for (int q = 0; q < 4; ++q) {
            int c = k * 4 + q;
            float v = x_proj_w[(size_t)j * DI + c];
            unsigned short h = f2bf(v);
            int idx = j * 256 + (c ^ sw);
            xwh[idx] = h;
            xwl[idx] = f2bf(v - bf2f(h));
        }
    }
}

// ---------------------------------------------------------------- K1: MFMA front-end + dt + chunk dt-sums
// phase A: xpre = z @ W1^T (hi/lo split MFMA) ; conv+silu -> x_bf + xt(LDS)
// phase B: x_dbl(0..23) via MFMA -> Bssm + dtin tile (LDS)
// phase C: dt = softplus(dtin @ dt_proj^T + b) -> dt_bf + Dcs (per-tile sums)
__global__ __launch_bounds__(256, 2) void k1_front(
    const float* __restrict__ z, const float* __restrict__ conv_w,
    const float* __restrict__ conv_b, const float* __restrict__ dt_proj_w,
    const float* __restrict__ dt_proj_b,
    const unsigned short* __restrict__ W1h, const unsigned short* __restrict__ W1l,
    const unsigned short* __restrict__ xwh, const unsigned short* __restrict__ xwl,
    const float* __restrict__ b1,
    float* __restrict__ Bssm, float* __restrict__ Dcs,
    __hip_bfloat16* __restrict__ x_bf, __hip_bfloat16* __restrict__ dt_bf,
    float* __restrict__ hlast)
{
    // region 1: xpre [48][258] f32 (49,536B); later reused as xt bf16 [48][512 u16, swizzled]
    __shared__ float xpre[48 * 258];
    // region 2: zt hi/lo bf16 (2*3072 u16); later reused as xw hi/lo bf16 (2*6144 u16)
    __shared__ unsigned short uB[12288];
    // region 3: dtin tile
    __shared__ float dtl[TT][8];

    int b = blockIdx.y, tile = blockIdx.x;
    int t0 = tile * TT;
    int t0m3 = t0 - 3;
    int tid = threadIdx.x;
    int lane = tid & 63, wid = tid >> 6;
    int l15 = lane & 15, l4 = lane >> 4;

    // zero hlast (poisoned workspace) -- done by tile-0 blocks, before k3b runs
    if (tile == 0) {
        float4 z4 = make_float4(0.f, 0.f, 0.f, 0.f);
        float4* hl4 = (float4*)(hlast + (size_t)b * (DS * DI));
        #pragma unroll
        for (int i = 0; i < 4; ++i) hl4[tid + i * 256] = z4;
    }

    // per-thread conv + dt params (channel d = tid)
    float4 cw = *(const float4*)(conv_w + tid * 4);
    float cb = conv_b[tid];
    float bias = b1[tid];
    float4 dwA = *(const float4*)(dt_proj_w + (size_t)tid * DR);
    float4 dwB = *(const float4*)(dt_proj_w + (size_t)tid * DR + 4);
    float dbias = dt_proj_b[tid];

    // ---- B-frags for phase A from W1 hi/lo (direct bf16 loads)
    v8bf wh[4][2], wl[4][2];
    {
        int d0w = wid * 64;
        #pragma unroll
        for (int nt = 0; nt < 4; ++nt) {
            int dr = d0w + nt * 16 + l15;
            #pragma unroll
            for (int kb = 0; kb < 2; ++kb) {
                int k0 = kb * 32 + l4 * 8;
                wh[nt][kb] = __builtin_bit_cast(v8bf, *(const v8us*)(W1h + (size_t)dr * LAT + k0));
                wl[nt][kb] = __builtin_bit_cast(v8bf, *(const v8us*)(W1l + (size_t)dr * LAT + k0));
            }
        }
    }

    // ---- stage z tile (48 rows incl history) as hi/lo bf16, XOR-swizzled rows
    {
        const float* zb = z + (size_t)b * L_ * LAT;
        for (int i = tid; i < 48 * 8; i += 256) {   // (row, 8-elem slot)
            int r = i >> 3, s = i & 7;
            int tg = t0m3 + r;
            float f[8];
            if (tg >= 0) {
                float4 u = *(const float4*)(zb + (size_t)tg * LAT + s * 8);
                float4 v = *(const float4*)(zb + (size_t)tg * LAT + s * 8 + 4);
                f[0]=u.x; f[1]=u.y; f[2]=u.z; f[3]=u.w; f[4]=v.x; f[5]=v.y; f[6]=v.z; f[7]=v.w;
            } else {
                #pragma unroll
                for (int q = 0; q < 8; ++q) f[q] = 0.f;
            }
            v8us hh, ll;
            #pragma unroll
            for (int q = 0; q < 8; ++q) {
                unsigned short h = f2bf(f[q]);
                hh[q] = h;
                ll[q] = f2bf(f[q] - bf2f(h));
            }
            int idx = r * 64 + ((s * 8) ^ ((r & 7) << 3));   // u16 units, 16B-aligned slots
            *(v8us*)&uB[idx] = hh;
            *(v8us*)&uB[3072 + idx] = ll;
        }
    }
    __syncthreads();

    // ---- phase A MFMA: 3 m-tiles x 4 n-tiles, K=64, 6 MFMA per tile (hi/lo cross terms)
    {
        int d0w = wid * 64;
        #pragma unroll
        for (int mt = 0; mt < 3; ++mt) {
            int r = mt * 16 + l15;
            int sw = (r & 7) << 3;
            int kb0 = l4 * 8;
            v8bf ah0 = __builtin_bit_cast(v8bf, *(const v8us*)&uB[r * 64 + (kb0 ^ sw)]);
            v8bf ah1 = __builtin_bit_cast(v8bf, *(const v8us*)&uB[r * 64 + ((32 + kb0) ^ sw)]);
            v8bf al0 = __builtin_bit_cast(v8bf, *(const v8us*)&uB[3072 + r * 64 + (kb0 ^ sw)]);
            v8bf al1 = __builtin_bit_cast(v8bf, *(const v8us*)&uB[3072 + r * 64 + ((32 + kb0) ^ sw)]);
            int rr = mt * 16 + l4 * 4;
            #pragma unroll
            for (int nt = 0; nt < 4; ++nt) {
                v4f acc = {0.f, 0.f, 0.f, 0.f};
                acc = MFMA16(ah0, wh[nt][0], acc);
                acc = MFMA16(ah1, wh[nt][1], acc);
                acc = MFMA16(ah0, wl[nt][0], acc);
                acc = MFMA16(ah1, wl[nt][1], acc);
                acc = MFMA16(al0, wh[nt][0], acc);
                acc = MFMA16(al1, wh[nt][1], acc);
                int cc = d0w + nt * 16 + l15;
                xpre[(rr + 0) * 258 + cc] = acc[0];
                xpre[(rr + 1) * 258 + cc] = acc[1];
                xpre[(rr + 2) * 258 + cc] = acc[2];
                xpre[(rr + 3) * 258 + cc] = acc[3];
            }
        }
    }

    // issue x_proj hi/lo global loads early (pre-swizzled; latency hides under conv)
    v8us xwr[6];
    {
        #pragma unroll
        for (int p = 0; p < 3; ++p) {
            xwr[p]     = *(const v8us*)(xwh + tid * 24 + p * 8);
            xwr[3 + p] = *(const v8us*)(xwl + tid * 24 + p * 8);
        }
    }
    __syncthreads();

    // ---- conv + silu per channel column (d = tid); keep x in registers
    float xr[TT];
    {
        int d = tid;
        float p0 = xpre[0 * 258 + d] + ((t0m3 + 0 >= 0) ? bias : 0.f);
        float p1 = xpre[1 * 258 + d] + ((t0m3 + 1 >= 0) ? bias : 0.f);
        float p2 = xpre[2 * 258 + d] + ((t0m3 + 2 >= 0) ? bias : 0.f);
        #pragma unroll
        for (int r = 3; r < 48; ++r) {
            float cur = xpre[r * 258 + d] + bias;
            float xc = cw.x * p0 + cw.y * p1 + cw.z * p2 + cw.w * cur + cb;
            xr[r - 3] = siluf(xc);
            p0 = p1; p1 = p2; p2 = cur;
        }
        __hip_bfloat16* xb = x_bf + ((size_t)b * L_ + t0) * DI + d;
        #pragma unroll
        for (int t = 0; t < TT; ++t)
            xb[(size_t)t * DI] = __float2bfloat16(xr[t]);
    }
    __syncthreads();   // xpre dead, zt dead

    // ---- write xt bf16 (swizzled, over xpre space); stage xw hi/lo (over zt space)
    unsigned short* xt16 = (unsigned short*)xpre;   // [48][512 u16], slot-swizzled
    {
        int d = tid;
        #pragma unroll
        for (int t = 0; t < TT; ++t)
            xt16[t * 512 + (d ^ ((t & 7) << 3))] = f2bf(xr[t]);
        #pragma unroll
        for (int t = TT; t < 48; ++t)
            xt16[t * 512 + (d ^ ((t & 7) << 3))] = 0;
        #pragma unroll
        for (int p = 0; p < 3; ++p) {
            *(v8us*)&uB[tid * 24 + p * 8] = xwr[p];
            *(v8us*)&uB[6144 + tid * 24 + p * 8] = xwr[3 + p];
        }
    }
    __syncthreads();

    // ---- phase B MFMA: x_dbl[t][j] = sum_k xt[t][k] * x_proj_w[j][k], j = 0..23
    if (wid < 3) {
        int mt = wid;
        int rA = mt * 16 + l15;
        int swA = (rA & 7) << 3;
        int jc0 = l15;
        int jc1 = 16 + l15; if (jc1 > 23) jc1 = 23;   // clamp (outputs >=24 discarded)
        v4f acc0 = {0.f, 0.f, 0.f, 0.f}, acc1 = {0.f, 0.f, 0.f, 0.f};
        #pragma unroll
        for (int kb = 0; kb < 8; ++kb) {
            int k0 = kb * 32 + l4 * 8;
            v8bf xa  = __builtin_bit_cast(v8bf, *(const v8us*)&xt16[rA * 512 + (k0 ^ swA)]);
            int s0 = k0 ^ ((jc0 & 7) << 3);
            int s1 = k0 ^ ((jc1 & 7) << 3);
            v8bf b0h = __builtin_bit_cast(v8bf, *(const v8us*)&uB[jc0 * 256 + s0]);
            v8bf b0l = __builtin_bit_cast(v8bf, *(const v8us*)&uB[6144 + jc0 * 256 + s0]);
            v8bf b1h = __builtin_bit_cast(v8bf, *(const v8us*)&uB[jc1 * 256 + s1]);
            v8bf b1l = __builtin_bit_cast(v8bf, *(const v8us*)&uB[6144 + jc1 * 256 + s1]);
            acc0 = MFMA16(xa, b0h, acc0);
            acc0 = MFMA16(xa, b0l, acc0);
            acc1 = MFMA16(xa, b1h, acc1);
            acc1 = MFMA16(xa, b1l, acc1);
        }
        int rr = mt * 16 + l4 * 4;
        #pragma unroll
        for (int reg = 0; reg < 4; ++reg) {
            int t = rr + reg;
            if (t < TT) {
                size_t tg = (size_t)b * L_ + (t0 + t);
                float v0 = acc0[reg], v1 = acc1[reg];
                if (l15 < 8) {
                    dtl[t][l15] = v0;                  // dt_in cols 0..7 -> LDS
                    Bssm[tg * DS + 8 + l15] = v1;      // B cols 8..15 (j = 16..23)
                } else {
                    Bssm[tg * DS + (l15 - 8)] = v0;    // B cols 0..7 (j = 8..15)
                }
            }
        }
    }
    __syncthreads();

    // ---- phase C: dt = softplus(dtin @ dt_proj^T + b); dt_bf + per-tile sum
    {
        int d = tid;
        __hip_bfloat16* dout = dt_bf + ((size_t)b * L_ + t0) * DI + d;
        float S = 0.f;
        #pragma unroll 5
        for (int t = 0; t < TT; ++t) {
            float4 u = *(const float4*)&dtl[t][0];
            float4 v = *(const float4*)&dtl[t][4];
            float r = dbias + u.x*dwA.x + u.y*dwA.y + u.z*dwA.z + u.w*dwA.w
                            + v.x*dwB.x + v.y*dwB.y + v.z*dwB.z + v.w*dwB.w;
            float dt = softplusf(r);
            dout[(size_t)t * DI] = __float2bfloat16(dt);
            S += dt;
        }
        Dcs[((size_t)b * NC + tile) * DI + d] = S;
    }
}

// ---------------------------------------------------------------- K3a2: suffix sums of chunk dt-sums
__global__ __launch_bounds__(256) void k3a2_suffix(
    const float* __restrict__ Dcs, float* __restrict__ Rsuf)
{
    int b = blockIdx.x, d = threadIdx.x;
    float R = 0.f;
    for (int c = NC - 1; c >= 0; --c) {
        Rsuf[((size_t)b * NC + c) * DI + d] = R;
        R += Dcs[((size_t)b * NC + c) * DI + d];
    }
}

// ---------------------------------------------------------------- K3b: streaming suffix reduction; atomic combine into hlast
__global__ __launch_bounds__(512) void k3b_scan(
    const __hip_bfloat16* __restrict__ x_bf, const __hip_bfloat16* __restrict__ dt_bf,
    const float* __restrict__ Bssm, const float* __restrict__ A_log,
    const float* __restrict__ Rsuf, float* __restrict__ hlast)
{
    int c = blockIdx.x, dg = blockIdx.y, b = blockIdx.z;
    int tid = threadIdx.x;
    int dh = tid & 31;
    int s  = ((tid >> 6) << 1) | ((tid >> 5) & 1);
    int d  = dg * 32 + dh;

    float a = -__expf(A_log[d * DS + s]);
    float R = Rsuf[((size_t)b * NC + c) * DI + d];

    float H = 0.f;
    float S_run = R;
    if (!__all(a * R < THR)) {
        int t0 = c * TC;
        const __hip_bfloat16* xp = x_bf + ((size_t)b * L_ + t0) * DI + d;
        const __hip_bfloat16* dp = dt_bf + ((size_t)b * L_ + t0) * DI + d;
        const float* Bp = Bssm + ((size_t)b * L_ + t0) * DS + s;
        {   // t = TT-1 single (45 = 11*4 + 1)
            float x4 = __bfloat162float(xp[(TC-1)*DI]);
            float d4 = __bfloat162float(dp[(TC-1)*DI]);
            float B4 = Bp[(TC-1)*DS];
            float e = __expf(a * S_run); H = fmaf(e * d4 * x4, B4, H); S_run += d4;
        }
        for (int j = TC - 5; j >= 0; j -= 4) {
            float x3 = __bfloat162float(xp[(j+3)*DI]);
            float x2 = __bfloat162float(xp[(j+2)*DI]);
            float x1 = __bfloat162float(xp[(j+1)*DI]);
            float x0 = __bfloat162float(xp[(j+0)*DI]);
            float d3 = __bfloat162float(dp[(j+3)*DI]);
            float d2 = __bfloat162float(dp[(j+2)*DI]);
            float d1 = __bfloat162float(dp[(j+1)*DI]);
            float d0 = __bfloat162float(dp[(j+0)*DI]);
            float B3 = Bp[(j+3)*DS];
            float B2 = Bp[(j+2)*DS];
            float B1 = Bp[(j+1)*DS];
            float B0 = Bp[(j+0)*DS];
            float e;
            e = __expf(a * S_run); H = fmaf(e * d3 * x3, B3, H); S_run += d3;
            e = __expf(a * S_run); H = fmaf(e * d2 * x2, B2, H); S_run += d2;
            e = __expf(a * S_run); H = fmaf(e * d1 * x1, B1, H); S_run += d1;
            e = __expf(a * S_run); H = fmaf(e * d0 * x0, B0, H); S_run += d0;
            if (__all(a * S_run < THR)) break;
        }
    }
    if (H != 0.f)
        atomicAdd(hlast + (((size_t)b * DS + s) * DI + d), H);
}

// ---------------------------------------------------------------- K4: the t = L-1 tail
__global__ __launch_bounds__(256) void k4_final(
    const float* __restrict__ z, const float* __restrict__ emb_w,
    const float* __restrict__ emb_b, const float* __restrict__ in_proj_w,
    const float* __restrict__ conv_w, const float* __restrict__ conv_b,
    const float* __restrict__ x_proj_w, const float* __restrict__ D_skip,
    const float* __restrict__ out_proj_w, const float* __restrict__ norm_w,
    const float* __restrict__ norm_b, const float* __restrict__ cls_w,
    const float* __restrict__ cls_b, const float* __restrict__ W1,
    const float* __restrict__ b1, const float* __restrict__ h_last,
    float* __restrict__ out)
{
    __shared__ float zl[4][64];
    __shared__ float xlast[DI];
    __shared__ float xemb[DM];
    __shared__ float Cl[DS];
    __shared__ float ylds[DI];
    __shared__ float olds[DM];
    int b = blockIdx.x, tid = threadIdx.x;
    {
        int r = tid >> 6, k = tid & 63;
        zl[r][k] = z[((size_t)b * L_ + (L_ - 4 + r)) * LAT + k];
    }
    __syncthreads();
    {   // x at t = L-1 (conv over last 4 x_pre)
        int d = tid;
        const float* wr = W1 + d * LAT;
        float xp[4];
        #pragma unroll
        for (int r = 0; r < 4; ++r) {
            float acc = b1[d];
            for (int k = 0; k < LAT; ++k) acc += zl[r][k] * wr[k];
            xp[r] = acc;
        }
        float4 cwv = *(const float4*)(conv_w + d * 4);
        float xc = cwv.x*xp[0] + cwv.y*xp[1] + cwv.z*xp[2] + cwv.w*xp[3] + conv_b[d];
        xlast[d] = siluf(xc);
    }
    __syncthreads();
    if (tid < DS) {   // C at L-1
        float acc = 0.f;
        const float* wr = x_proj_w + (size_t)(DR + DS + tid) * DI;
        for (int k = 0; k < DI; ++k) acc += xlast[k] * wr[k];
        Cl[tid] = acc;
    }
    if (tid >= 64 && tid < 64 + DM) {   // x_emb at L-1 (for z-branch)
        int m = tid - 64;
        float acc = emb_b[m];
        const float* wr = emb_w + (size_t)m * LAT;
        for (int k = 0; k < LAT; ++k) acc += zl[3][k] * wr[k];
        xemb[m] = acc;
    }
    __syncthreads();
    {   // y = (h.C) + x*D_skip, gated by silu(z-branch)
        int d = tid;
        float hs = 0.f;
        #pragma unroll
        for (int si = 0; si < DS; ++si)
            hs += h_last[((size_t)b * DS + si) * DI + d] * Cl[si];
        float y = hs + xlast[d] * D_skip[d];
        float zbv = 0.f;
        const float* wr = in_proj_w + (size_t)(DI + d) * DM;
        for (int m = 0; m < DM; ++m) zbv += xemb[m] * wr[m];
        y *= siluf(zbv);
        ylds[d] = y;
    }
    __syncthreads();
    if (tid < DM) {   // out_proj
        float acc = 0.f;
        const float* wr = out_proj_w + (size_t)tid * DI;
        for (int k = 0; k < DI; ++k) acc += ylds[k] * wr[k];
        olds[tid] = acc;
    }
    __syncthreads();
    if (tid < 64) {   // LayerNorm + classifier (one wave)
        float v0 = olds[tid], v1 = olds[tid + 64];
        float sum = v0 + v1;
        #pragma unroll
        for (int off = 32; off > 0; off >>= 1) sum += __shfl_down(sum, off);
        float mu = __shfl(sum, 0) * (1.0f / 128.0f);
        float dv0 = v0 - mu, dv1 = v1 - mu;
        float vs = dv0 * dv0 + dv1 * dv1;
        #pragma unroll
        for (int off = 32; off > 0; off >>= 1) vs += __shfl_down(vs, off);
        float var = __shfl(vs, 0) * (1.0f / 128.0f);
        float rstd = rsqrtf(var + 1e-5f);
        float xn0 = dv0 * rstd * norm_w[tid] + norm_b[tid];
        float xn1 = dv1 * rstd * norm_w[tid + 64] + norm_b[tid + 64];
        float lg = xn0 * cls_w[tid] + xn1 * cls_w[tid + 64];
        #pragma unroll
        for (int off = 32; off > 0; off >>= 1) lg += __shfl_down(lg, off);
        if (tid == 0) out[b] = lg + cls_b[0];
    }
}

// ---------------------------------------------------------------- launch
extern "C" void kernel_launch(void* const* d_in, const int* in_sizes, int n_in,
                              void* d_out, int out_size, void* d_ws, size_t ws_size,
                              hipStream_t stream) {
    (void)in_sizes; (void)n_in; (void)out_size;
    const float* z         = (const float*)d_in[0];
    const float* emb_w     = (const float*)d_in[1];
    const float* emb_b     = (const float*)d_in[2];
    const float* in_proj_w = (const float*)d_in[3];
    const float* conv_w    = (const float*)d_in[4];
    const float* conv_b    = (const float*)d_in[5];
    const float* x_proj_w  = (const float*)d_in[6];
    const float* dt_proj_w = (const float*)d_in[7];
    const float* dt_proj_b = (const float*)d_in[8];
    const float* A_log     = (const float*)d_in[9];
    const float* D_skip    = (const float*)d_in[10];
    const float* out_proj_w= (const float*)d_in[11];
    const float* norm_w    = (const float*)d_in[12];
    const float* norm_b    = (const float*)d_in[13];
    const float* cls_w     = (const float*)d_in[14];
    const float* cls_b     = (const float*)d_in[15];
    float* out = (float*)d_out;

    float* ws    = (float*)d_ws;
    float* W1    = ws;                       // 16384 f
    float* b1    = W1 + 16384;               // 256 f
    float* Bssm  = b1 + 256;                 // 16*3600*16  = 921600 f
    float* Dcs   = Bssm + 921600;            // 16*80*256   = 327680 f
    float* Rsuf  = Dcs + 327680;             // 327680 f
    float* hlast = Rsuf + 327680;            // 16*16*256   = 65536 f
    float* fend  = hlast + 65536;
    unsigned short* W1h  = (unsigned short*)fend;             // 16384 u16
    unsigned short* W1l  = W1h + 16384;                       // 16384 u16
    unsigned short* xwh  = W1l + 16384;                       // 24*256 = 6144 u16
    unsigned short* xwl  = xwh + 6144;                        // 6144 u16
    __hip_bfloat16* x_bf  = (__hip_bfloat16*)(xwl + 6144);    // 16*3600*256 bf16
    __hip_bfloat16* dt_bf = x_bf + (size_t)B_ * L_ * DI;      // 16*3600*256 bf16
    size_t needed = ((size_t)(16384 + 256 + 921600 + 327680 + 327680 + 65536)) * 4
                  + ((size_t)(16384 + 16384 + 6144 + 6144)) * 2
                  + (size_t)B_ * L_ * DI * 2 * 2;
    if (ws_size < needed) return;

    k0_combine <<<dim3(DI + 24),     dim3(LAT), 0, stream>>>(in_proj_w, emb_w, emb_b, x_proj_w,
                                                             W1, b1, W1h, W1l, xwh, xwl);
    k1_front   <<<dim3(NT, B_),      dim3(256), 0, stream>>>(z, conv_w, conv_b, dt_proj_w, dt_proj_b,
                                                             W1h, W1l, xwh, xwl, b1,
                                                             Bssm, Dcs, x_bf, dt_bf, hlast);
    k3a2_suffix<<<dim3(B_),          dim3(256), 0, stream>>>(Dcs, Rsuf);
    k3b_scan   <<<dim3(NC, 8, B_),   dim3(512), 0, stream>>>(x_bf, dt_bf, Bssm, A_log, Rsuf, hlast);
    k4_final   <<<dim3(B_),          dim3(256), 0, stream>>>(z, emb_w, emb_b, in_proj_w, conv_w, conv_b,
                                                             x_proj_w, D_skip, out_proj_w, norm_w, norm_b,
                                                             cls_w, cls_b, W1, b1, hlast, out);
}

// Round 4
// 116.073 us; speedup vs baseline: 2.1866x; 1.0476x over previous
//
#include <hip/hip_runtime.h>
#include <hip/hip_bf16.h>
#include <math.h>

#define B_  16
#define L_  3600
#define LAT 64
#define DM  128
#define DI  256
#define DS  16
#define DR  8

#define TT  45    // K1 time-tile == scan chunk length
#define NT  80    // 3600/45 tiles == chunks
#define NC  80
#define TC  45
#define THR (-20.0f)   // exp(a*S) < exp(-20) ~ 2e-9 -> negligible

typedef __bf16 v8bf __attribute__((ext_vector_type(8)));
typedef float  v4f  __attribute__((ext_vector_type(4)));
typedef unsigned short v8us __attribute__((ext_vector_type(8)));

#define MFMA16(A, Bf, C) __builtin_amdgcn_mfma_f32_16x16x32_bf16((A), (Bf), (C), 0, 0, 0)

__device__ __forceinline__ float siluf(float v) {
    return v * __builtin_amdgcn_rcpf(1.0f + __expf(-v));
}
__device__ __forceinline__ float softplusf(float v) {
    float r = __logf(1.0f + __expf(v));
    return (v > 15.0f) ? v : r;
}
__device__ __forceinline__ float bf2f(unsigned short u) {
    unsigned int x = ((unsigned int)u) << 16;
    return __builtin_bit_cast(float, x);
}
__device__ __forceinline__ unsigned short f2bf(float f) {
    __hip_bfloat16 h = __float2bfloat16(f);
    return __builtin_bit_cast(unsigned short, h);
}

// ---------------------------------------------------------------- K0: W1 = in_proj_x @ emb_w (+ hi/lo bf16), b1; pre-swizzled x_proj hi/lo
__global__ __launch_bounds__(64) void k0_combine(
    const float* __restrict__ in_proj_w, const float* __restrict__ emb_w,
    const float* __restrict__ emb_b, const float* __restrict__ x_proj_w,
    float* __restrict__ W1, float* __restrict__ b1,
    unsigned short* __restrict__ W1h, unsigned short* __restrict__ W1l,
    unsigned short* __restrict__ xwh, unsigned short* __restrict__ xwl)
{
    int blk = blockIdx.x, k = threadIdx.x;
    if (blk < DI) {
        int d = blk;
        const float* row = in_proj_w + (size_t)d * DM;
        float acc = 0.f;
        for (int m = 0; m < DM; ++m) acc += row[m] * emb_w[m * LAT + k];
        W1[d * LAT + k] = acc;
        unsigned short h = f2bf(acc);
        W1h[d * LAT + k] = h;
        W1l[d * LAT + k] = f2bf(acc - bf2f(h));
        if (k == 0) {
            float ab = 0.f;
            for (int m = 0; m < DM; ++m) ab += row[m] * emb_b[m];
            b1[d] = ab;
        }
    } else {
        int j = blk - DI;   // 0..23
        int sw = (j & 7) << 3;
        #pragma unroll
        for (int q = 0; q < 4; ++q) {
            int c = k * 4 + q;
            float v = x_proj_w[(size_t)j * DI + c];
            unsigned short h = f2bf(v);
            int idx = j * 256 + (c ^ sw);
            xwh[idx] = h;
            xwl[idx] = f2bf(v - bf2f(h));
        }
    }
}

// ---------------------------------------------------------------- K1: MFMA front-end + dt + chunk dt-sums
// LDS byte map (peak 49,152 + dtl 1,440 = 50.6 KB -> 3 blocks/CU):
//   phase A/conv : [0,32896) xpre f32[32][257] (rows mod 32) | [32896,39040) z-hi | [39040,45184) z-lo
//   phase B      : [0,24576) xt16 u16[48][256] swz | [24576,36864) xw-hi | [36864,49152) xw-lo
__global__ __launch_bounds__(256, 3) void k1_front(
    const float* __restrict__ z, const float* __restrict__ conv_w,
    const float* __restrict__ conv_b, const float* __restrict__ dt_proj_w,
    const float* __restrict__ dt_proj_b,
    const unsigned short* __restrict__ W1h, const unsigned short* __restrict__ W1l,
    const unsigned short* __restrict__ xwh, const unsigned short* __restrict__ xwl,
    const float* __restrict__ b1,
    float* __restrict__ Bssm, float* __restrict__ Dcs,
    unsigned int* __restrict__ xd, float* __restrict__ hlast)
{
    __shared__ __align__(16) unsigned char smem[49152];
    __shared__ float dtl[TT][8];
    float* xpre = (float*)smem;                              // [32][257]
    unsigned short* zth = (unsigned short*)(smem + 32896);   // 3072 u16
    unsigned short* ztl = (unsigned short*)(smem + 39040);   // 3072 u16
    unsigned short* xt16 = (unsigned short*)smem;            // [48][256] swz
    unsigned short* xwhL = (unsigned short*)(smem + 24576);  // 6144 u16
    unsigned short* xwlL = (unsigned short*)(smem + 36864);  // 6144 u16

    int b = blockIdx.y, tile = blockIdx.x;
    int t0 = tile * TT;
    int t0m3 = t0 - 3;
    int tid = threadIdx.x;
    int lane = tid & 63, wid = tid >> 6;
    int l15 = lane & 15, l4 = lane >> 4;

    // zero hlast (poisoned workspace) -- done by tile-0 blocks, before k3b runs
    if (tile == 0) {
        float4 z4 = make_float4(0.f, 0.f, 0.f, 0.f);
        float4* hl4 = (float4*)(hlast + (size_t)b * (DS * DI));
        #pragma unroll
        for (int i = 0; i < 4; ++i) hl4[tid + i * 256] = z4;
    }

    // per-thread conv + dt params (channel d = tid)
    float4 cw = *(const float4*)(conv_w + tid * 4);
    float cb = conv_b[tid];
    float bias = b1[tid];
    float4 dwA = *(const float4*)(dt_proj_w + (size_t)tid * DR);
    float4 dwB = *(const float4*)(dt_proj_w + (size_t)tid * DR + 4);
    float dbias = dt_proj_b[tid];

    // ---- B-frags for phase A from W1 hi/lo (direct bf16 loads)
    v8bf wh[4][2], wl[4][2];
    {
        int d0w = wid * 64;
        #pragma unroll
        for (int nt = 0; nt < 4; ++nt) {
            int dr = d0w + nt * 16 + l15;
            #pragma unroll
            for (int kb = 0; kb < 2; ++kb) {
                int k0 = kb * 32 + l4 * 8;
                wh[nt][kb] = __builtin_bit_cast(v8bf, *(const v8us*)(W1h + (size_t)dr * LAT + k0));
                wl[nt][kb] = __builtin_bit_cast(v8bf, *(const v8us*)(W1l + (size_t)dr * LAT + k0));
            }
        }
    }

    // ---- stage z tile (48 rows incl history) as hi/lo bf16, XOR-swizzled rows
    {
        const float* zb = z + (size_t)b * L_ * LAT;
        for (int i = tid; i < 48 * 8; i += 256) {   // (row, 8-elem slot)
            int r = i >> 3, s = i & 7;
            int tg = t0m3 + r;
            float f[8];
            if (tg >= 0) {
                float4 u = *(const float4*)(zb + (size_t)tg * LAT + s * 8);
                float4 v = *(const float4*)(zb + (size_t)tg * LAT + s * 8 + 4);
                f[0]=u.x; f[1]=u.y; f[2]=u.z; f[3]=u.w; f[4]=v.x; f[5]=v.y; f[6]=v.z; f[7]=v.w;
            } else {
                #pragma unroll
                for (int q = 0; q < 8; ++q) f[q] = 0.f;
            }
            v8us hh, ll;
            #pragma unroll
            for (int q = 0; q < 8; ++q) {
                unsigned short h = f2bf(f[q]);
                hh[q] = h;
                ll[q] = f2bf(f[q] - bf2f(h));
            }
            int idx = r * 64 + ((s * 8) ^ ((r & 7) << 3));   // u16 units, 16B-aligned slots
            *(v8us*)&zth[idx] = hh;
            *(v8us*)&ztl[idx] = ll;
        }
    }
    __syncthreads();

    // ---- phase A1 MFMA: m-tiles 0,1 (rows 0..31)
    int d0w = wid * 64;
    #pragma unroll
    for (int mt = 0; mt < 2; ++mt) {
        int r = mt * 16 + l15;
        int sw = (r & 7) << 3;
        int kb0 = l4 * 8;
        v8bf ah0 = __builtin_bit_cast(v8bf, *(const v8us*)&zth[r * 64 + (kb0 ^ sw)]);
        v8bf ah1 = __builtin_bit_cast(v8bf, *(const v8us*)&zth[r * 64 + ((32 + kb0) ^ sw)]);
        v8bf al0 = __builtin_bit_cast(v8bf, *(const v8us*)&ztl[r * 64 + (kb0 ^ sw)]);
        v8bf al1 = __builtin_bit_cast(v8bf, *(const v8us*)&ztl[r * 64 + ((32 + kb0) ^ sw)]);
        int rr = mt * 16 + l4 * 4;
        #pragma unroll
        for (int nt = 0; nt < 4; ++nt) {
            v4f acc = {0.f, 0.f, 0.f, 0.f};
            acc = MFMA16(ah0, wh[nt][0], acc);
            acc = MFMA16(ah1, wh[nt][1], acc);
            acc = MFMA16(ah0, wl[nt][0], acc);
            acc = MFMA16(ah1, wl[nt][1], acc);
            acc = MFMA16(al0, wh[nt][0], acc);
            acc = MFMA16(al1, wh[nt][1], acc);
            int cc = d0w + nt * 16 + l15;
            xpre[(rr + 0) * 257 + cc] = acc[0];
            xpre[(rr + 1) * 257 + cc] = acc[1];
            xpre[(rr + 2) * 257 + cc] = acc[2];
            xpre[(rr + 3) * 257 + cc] = acc[3];
        }
    }

    // issue x_proj hi/lo global loads early (pre-swizzled; latency hides under conv)
    v8us xwr[6];
    {
        #pragma unroll
        for (int p = 0; p < 3; ++p) {
            xwr[p]     = *(const v8us*)(xwh + tid * 24 + p * 8);
            xwr[3 + p] = *(const v8us*)(xwl + tid * 24 + p * 8);
        }
    }
    __syncthreads();

    // ---- conv part 1: rows 0..31 -> xr[0..28]
    float xr[TT];
    float p0, p1, p2;
    {
        int d = tid;
        p0 = xpre[0 * 257 + d] + ((t0m3 + 0 >= 0) ? bias : 0.f);
        p1 = xpre[1 * 257 + d] + ((t0m3 + 1 >= 0) ? bias : 0.f);
        p2 = xpre[2 * 257 + d] + ((t0m3 + 2 >= 0) ? bias : 0.f);
        #pragma unroll
        for (int r = 3; r < 32; ++r) {
            float cur = xpre[r * 257 + d] + bias;
            float xc = cw.x * p0 + cw.y * p1 + cw.z * p2 + cw.w * cur + cb;
            xr[r - 3] = siluf(xc);
            p0 = p1; p1 = p2; p2 = cur;
        }
    }
    __syncthreads();   // conv1 reads done; xpre reusable

    // ---- phase A2 MFMA: m-tile 2 (rows 32..47 -> xpre rows 0..15)
    {
        int r = 32 + l15;
        int sw = (r & 7) << 3;
        int kb0 = l4 * 8;
        v8bf ah0 = __builtin_bit_cast(v8bf, *(const v8us*)&zth[r * 64 + (kb0 ^ sw)]);
        v8bf ah1 = __builtin_bit_cast(v8bf, *(const v8us*)&zth[r * 64 + ((32 + kb0) ^ sw)]);
        v8bf al0 = __builtin_bit_cast(v8bf, *(const v8us*)&ztl[r * 64 + (kb0 ^ sw)]);
        v8bf al1 = __builtin_bit_cast(v8bf, *(const v8us*)&ztl[r * 64 + ((32 + kb0) ^ sw)]);
        int rr = l4 * 4;
        #pragma unroll
        for (int nt = 0; nt < 4; ++nt) {
            v4f acc = {0.f, 0.f, 0.f, 0.f};
            acc = MFMA16(ah0, wh[nt][0], acc);
            acc = MFMA16(ah1, wh[nt][1], acc);
            acc = MFMA16(ah0, wl[nt][0], acc);
            acc = MFMA16(ah1, wl[nt][1], acc);
            acc = MFMA16(al0, wh[nt][0], acc);
            acc = MFMA16(al1, wh[nt][1], acc);
            int cc = d0w + nt * 16 + l15;
            xpre[(rr + 0) * 257 + cc] = acc[0];
            xpre[(rr + 1) * 257 + cc] = acc[1];
            xpre[(rr + 2) * 257 + cc] = acc[2];
            xpre[(rr + 3) * 257 + cc] = acc[3];
        }
    }
    __syncthreads();

    // ---- conv part 2: rows 32..47 -> xr[29..44]
    {
        int d = tid;
        #pragma unroll
        for (int r = 32; r < 48; ++r) {
            float cur = xpre[(r - 32) * 257 + d] + bias;
            float xc = cw.x * p0 + cw.y * p1 + cw.z * p2 + cw.w * cur + cb;
            xr[r - 3] = siluf(xc);
            p0 = p1; p1 = p2; p2 = cur;
        }
    }
    __syncthreads();   // xpre dead, zt dead

    // ---- write xt bf16 (swizzled, over xpre space); stage xw hi/lo
    {
        int d = tid;
        #pragma unroll
        for (int t = 0; t < TT; ++t)
            xt16[t * 256 + (d ^ ((t & 7) << 3))] = f2bf(xr[t]);
        #pragma unroll
        for (int t = TT; t < 48; ++t)
            xt16[t * 256 + (d ^ ((t & 7) << 3))] = 0;
        #pragma unroll
        for (int p = 0; p < 3; ++p) {
            *(v8us*)&xwhL[tid * 24 + p * 8] = xwr[p];
            *(v8us*)&xwlL[tid * 24 + p * 8] = xwr[3 + p];
        }
    }
    __syncthreads();

    // ---- phase B MFMA: x_dbl[t][j] = sum_k xt[t][k] * x_proj_w[j][k], j = 0..23
    if (wid < 3) {
        int mt = wid;
        int rA = mt * 16 + l15;
        int swA = (rA & 7) << 3;
        int jc0 = l15;
        int jc1 = 16 + l15; if (jc1 > 23) jc1 = 23;   // clamp (outputs >=24 discarded)
        v4f acc0 = {0.f, 0.f, 0.f, 0.f}, acc1 = {0.f, 0.f, 0.f, 0.f};
        #pragma unroll
        for (int kb = 0; kb < 8; ++kb) {
            int k0 = kb * 32 + l4 * 8;
            v8bf xa  = __builtin_bit_cast(v8bf, *(const v8us*)&xt16[rA * 256 + (k0 ^ swA)]);
            int s0 = k0 ^ ((jc0 & 7) << 3);
            int s1 = k0 ^ ((jc1 & 7) << 3);
            v8bf b0h = __builtin_bit_cast(v8bf, *(const v8us*)&xwhL[jc0 * 256 + s0]);
            v8bf b0l = __builtin_bit_cast(v8bf, *(const v8us*)&xwlL[jc0 * 256 + s0]);
            v8bf b1h = __builtin_bit_cast(v8bf, *(const v8us*)&xwhL[jc1 * 256 + s1]);
            v8bf b1l = __builtin_bit_cast(v8bf, *(const v8us*)&xwlL[jc1 * 256 + s1]);
            acc0 = MFMA16(xa, b0h, acc0);
            acc0 = MFMA16(xa, b0l, acc0);
            acc1 = MFMA16(xa, b1h, acc1);
            acc1 = MFMA16(xa, b1l, acc1);
        }
        int rr = mt * 16 + l4 * 4;
        #pragma unroll
        for (int reg = 0; reg < 4; ++reg) {
            int t = rr + reg;
            if (t < TT) {
                size_t tg = (size_t)b * L_ + (t0 + t);
                float v0 = acc0[reg], v1 = acc1[reg];
                if (l15 < 8) {
                    dtl[t][l15] = v0;                  // dt_in cols 0..7 -> LDS
                    Bssm[tg * DS + 8 + l15] = v1;      // B cols 8..15 (j = 16..23)
                } else {
                    Bssm[tg * DS + (l15 - 8)] = v0;    // B cols 0..7 (j = 8..15)
                }
            }
        }
    }
    __syncthreads();

    // ---- phase C: dt = softplus(dtin @ dt_proj^T + b); packed (x,dt) store + per-tile sum
    {
        int d = tid;
        unsigned int* xdout = xd + ((size_t)b * L_ + t0) * DI + d;
        float S = 0.f;
        #pragma unroll 5
        for (int t = 0; t < TT; ++t) {
            float4 u = *(const float4*)&dtl[t][0];
            float4 v = *(const float4*)&dtl[t][4];
            float r = dbias + u.x*dwA.x + u.y*dwA.y + u.z*dwA.z + u.w*dwA.w
                            + v.x*dwB.x + v.y*dwB.y + v.z*dwB.z + v.w*dwB.w;
            float dt = softplusf(r);
            unsigned int pack = ((unsigned int)f2bf(dt) << 16) | (unsigned int)f2bf(xr[t]);
            xdout[(size_t)t * DI] = pack;
            S += dt;
        }
        Dcs[((size_t)b * NC + tile) * DI + d] = S;
    }
}

// ---------------------------------------------------------------- K3a2: suffix sums of chunk dt-sums
__global__ __launch_bounds__(256) void k3a2_suffix(
    const float* __restrict__ Dcs, float* __restrict__ Rsuf)
{
    int b = blockIdx.x, d = threadIdx.x;
    float R = 0.f;
    for (int c = NC - 1; c >= 0; --c) {
        Rsuf[((size_t)b * NC + c) * DI + d] = R;
        R += Dcs[((size_t)b * NC + c) * DI + d];
    }
}

// ---------------------------------------------------------------- K3b: streaming suffix reduction; atomic combine into hlast
__global__ __launch_bounds__(512) void k3b_scan(
    const unsigned int* __restrict__ xd,
    const float* __restrict__ Bssm, const float* __restrict__ A_log,
    const float* __restrict__ Rsuf, float* __restrict__ hlast)
{
    int c = blockIdx.x, dg = blockIdx.y, b = blockIdx.z;
    int tid = threadIdx.x;
    int dh = tid & 31;
    int s  = ((tid >> 6) << 1) | ((tid >> 5) & 1);
    int d  = dg * 32 + dh;

    float a = -__expf(A_log[d * DS + s]);
    float R = Rsuf[((size_t)b * NC + c) * DI + d];

    float H = 0.f;
    float S_run = R;
    if (!__all(a * R < THR)) {
        int t0 = c * TC;
        const unsigned int* xp = xd + ((size_t)b * L_ + t0) * DI + d;
        const float* Bp = Bssm + ((size_t)b * L_ + t0) * DS + s;
        {   // t = TT-1 single (45 = 11*4 + 1)
            unsigned int u4 = xp[(TC-1)*DI];
            float x4 = bf2f((unsigned short)(u4 & 0xffff));
            float d4 = bf2f((unsigned short)(u4 >> 16));
            float B4 = Bp[(TC-1)*DS];
            float e = __expf(a * S_run); H = fmaf(e * d4 * x4, B4, H); S_run += d4;
        }
        for (int j = TC - 5; j >= 0; j -= 4) {
            unsigned int u3 = xp[(j+3)*DI];
            unsigned int u2 = xp[(j+2)*DI];
            unsigned int u1 = xp[(j+1)*DI];
            unsigned int u0 = xp[(j+0)*DI];
            float x3 = bf2f((unsigned short)(u3 & 0xffff)), d3 = bf2f((unsigned short)(u3 >> 16));
            float x2 = bf2f((unsigned short)(u2 & 0xffff)), d2 = bf2f((unsigned short)(u2 >> 16));
            float x1 = bf2f((unsigned short)(u1 & 0xffff)), d1 = bf2f((unsigned short)(u1 >> 16));
            float x0 = bf2f((unsigned short)(u0 & 0xffff)), d0 = bf2f((unsigned short)(u0 >> 16));
            float B3 = Bp[(j+3)*DS];
            float B2 = Bp[(j+2)*DS];
            float B1 = Bp[(j+1)*DS];
            float B0 = Bp[(j+0)*DS];
            float e;
            e = __expf(a * S_run); H = fmaf(e * d3 * x3, B3, H); S_run += d3;
            e = __expf(a * S_run); H = fmaf(e * d2 * x2, B2, H); S_run += d2;
            e = __expf(a * S_run); H = fmaf(e * d1 * x1, B1, H); S_run += d1;
            e = __expf(a * S_run); H = fmaf(e * d0 * x0, B0, H); S_run += d0;
            if (__all(a * S_run < THR)) break;
        }
    }
    if (H != 0.f)
        atomicAdd(hlast + (((size_t)b * DS + s) * DI + d), H);
}

// ---------------------------------------------------------------- K4: the t = L-1 tail
__global__ __launch_bounds__(256) void k4_final(
    const float* __restrict__ z, const float* __restrict__ emb_w,
    const float* __restrict__ emb_b, const float* __restrict__ in_proj_w,
    const float* __restrict__ conv_w, const float* __restrict__ conv_b,
    const float* __restrict__ x_proj_w, const float* __restrict__ D_skip,
    const float* __restrict__ out_proj_w, const float* __restrict__ norm_w,
    const float* __restrict__ norm_b, const float* __restrict__ cls_w,
    const float* __restrict__ cls_b, const float* __restrict__ W1,
    const float* __restrict__ b1, const float* __restrict__ h_last,
    float* __restrict__ out)
{
    __shared__ float zl[4][64];
    __shared__ float xlast[DI];
    __shared__ float xemb[DM];
    __shared__ float Cl[DS];
    __shared__ float ylds[DI];
    __shared__ float olds[DM];
    int b = blockIdx.x, tid = threadIdx.x;
    {
        int r = tid >> 6, k = tid & 63;
        zl[r][k] = z[((size_t)b * L_ + (L_ - 4 + r)) * LAT + k];
    }
    __syncthreads();
    {   // x at t = L-1 (conv over last 4 x_pre)
        int d = tid;
        const float* wr = W1 + d * LAT;
        float xp[4];
        #pragma unroll
        for (int r = 0; r < 4; ++r) {
            float acc = b1[d];
            for (int k = 0; k < LAT; ++k) acc += zl[r][k] * wr[k];
            xp[r] = acc;
        }
        float4 cwv = *(const float4*)(conv_w + d * 4);
        float xc = cwv.x*xp[0] + cwv.y*xp[1] + cwv.z*xp[2] + cwv.w*xp[3] + conv_b[d];
        xlast[d] = siluf(xc);
    }
    __syncthreads();
    if (tid < DS) {   // C at L-1
        float acc = 0.f;
        const float* wr = x_proj_w + (size_t)(DR + DS + tid) * DI;
        for (int k = 0; k < DI; ++k) acc += xlast[k] * wr[k];
        Cl[tid] = acc;
    }
    if (tid >= 64 && tid < 64 + DM) {   // x_emb at L-1 (for z-branch)
        int m = tid - 64;
        float acc = emb_b[m];
        const float* wr = emb_w + (size_t)m * LAT;
        for (int k = 0; k < LAT; ++k) acc += zl[3][k] * wr[k];
        xemb[m] = acc;
    }
    __syncthreads();
    {   // y = (h.C) + x*D_skip, gated by silu(z-branch)
        int d = tid;
        float hs = 0.f;
        #pragma unroll
        for (int si = 0; si < DS; ++si)
            hs += h_last[((size_t)b * DS + si) * DI + d] * Cl[si];
        float y = hs + xlast[d] * D_skip[d];
        float zbv = 0.f;
        const float* wr = in_proj_w + (size_t)(DI + d) * DM;
        for (int m = 0; m < DM; ++m) zbv += xemb[m] * wr[m];
        y *= siluf(zbv);
        ylds[d] = y;
    }
    __syncthreads();
    if (tid < DM) {   // out_proj
        float acc = 0.f;
        const float* wr = out_proj_w + (size_t)tid * DI;
        for (int k = 0; k < DI; ++k) acc += ylds[k] * wr[k];
        olds[tid] = acc;
    }
    __syncthreads();
    if (tid < 64) {   // LayerNorm + classifier (one wave)
        float v0 = olds[tid], v1 = olds[tid + 64];
        float sum = v0 + v1;
        #pragma unroll
        for (int off = 32; off > 0; off >>= 1) sum += __shfl_down(sum, off);
        float mu = __shfl(sum, 0) * (1.0f / 128.0f);
        float dv0 = v0 - mu, dv1 = v1 - mu;
        float vs = dv0 * dv0 + dv1 * dv1;
        #pragma unroll
        for (int off = 32; off > 0; off >>= 1) vs += __shfl_down(vs, off);
        float var = __shfl(vs, 0) * (1.0f / 128.0f);
        float rstd = rsqrtf(var + 1e-5f);
        float xn0 = dv0 * rstd * norm_w[tid] + norm_b[tid];
        float xn1 = dv1 * rstd * norm_w[tid + 64] + norm_b[tid + 64];
        float lg = xn0 * cls_w[tid] + xn1 * cls_w[tid + 64];
        #pragma unroll
        for (int off = 32; off > 0; off >>= 1) lg += __shfl_down(lg, off);
        if (tid == 0) out[b] = lg + cls_b[0];
    }
}

// ---------------------------------------------------------------- launch
extern "C" void kernel_launch(void* const* d_in, const int* in_sizes, int n_in,
                              void* d_out, int out_size, void* d_ws, size_t ws_size,
                              hipStream_t stream) {
    (void)in_sizes; (void)n_in; (void)out_size;
    const float* z         = (const float*)d_in[0];
    const float* emb_w     = (const float*)d_in[1];
    const float* emb_b     = (const float*)d_in[2];
    const float* in_proj_w = (const float*)d_in[3];
    const float* conv_w    = (const float*)d_in[4];
    const float* conv_b    = (const float*)d_in[5];
    const float* x_proj_w  = (const float*)d_in[6];
    const float* dt_proj_w = (const float*)d_in[7];
    const float* dt_proj_b = (const float*)d_in[8];
    const float* A_log     = (const float*)d_in[9];
    const float* D_skip    = (const float*)d_in[10];
    const float* out_proj_w= (const float*)d_in[11];
    const float* norm_w    = (const float*)d_in[12];
    const float* norm_b    = (const float*)d_in[13];
    const float* cls_w     = (const float*)d_in[14];
    const float* cls_b     = (const float*)d_in[15];
    float* out = (float*)d_out;

    float* ws    = (float*)d_ws;
    float* W1    = ws;                       // 16384 f
    float* b1    = W1 + 16384;               // 256 f
    float* Bssm  = b1 + 256;                 // 16*3600*16  = 921600 f
    float* Dcs   = Bssm + 921600;            // 16*80*256   = 327680 f
    float* Rsuf  = Dcs + 327680;             // 327680 f
    float* hlast = Rsuf + 327680;            // 16*16*256   = 65536 f
    float* fend  = hlast + 65536;
    unsigned short* W1h  = (unsigned short*)fend;             // 16384 u16
    unsigned short* W1l  = W1h + 16384;                       // 16384 u16
    unsigned short* xwh  = W1l + 16384;                       // 24*256 = 6144 u16
    unsigned short* xwl  = xwh + 6144;                        // 6144 u16
    unsigned int*   xd   = (unsigned int*)(xwl + 6144);       // 16*3600*256 u32 (x lo, dt hi)
    size_t needed = ((size_t)(16384 + 256 + 921600 + 327680 + 327680 + 65536)) * 4
                  + ((size_t)(16384 + 16384 + 6144 + 6144)) * 2
                  + (size_t)B_ * L_ * DI * 4;
    if (ws_size < needed) return;

    k0_combine <<<dim3(DI + 24),     dim3(LAT), 0, stream>>>(in_proj_w, emb_w, emb_b, x_proj_w,
                                                             W1, b1, W1h, W1l, xwh, xwl);
    k1_front   <<<dim3(NT, B_),      dim3(256), 0, stream>>>(z, conv_w, conv_b, dt_proj_w, dt_proj_b,
                                                             W1h, W1l, xwh, xwl, b1,
                                                             Bssm, Dcs, xd, hlast);
    k3a2_suffix<<<dim3(B_),          dim3(256), 0, stream>>>(Dcs, Rsuf);
    k3b_scan   <<<dim3(NC, 8, B_),   dim3(512), 0, stream>>>(xd, Bssm, A_log, Rsuf, hlast);
    k4_final   <<<dim3(B_),          dim3(256), 0, stream>>>(z, emb_w, emb_b, in_proj_w, conv_w, conv_b,
                                                             x_proj_w, D_skip, out_proj_w, norm_w, norm_b,
                                                             cls_w, cls_b, W1, b1, hlast, out);
}